// Round 1
// 803.627 us; speedup vs baseline: 1.0577x; 1.0577x over previous
//
#include <hip/hip_runtime.h>
#include <hip/hip_fp16.h>
#include <math.h>

#define HID 32
#define BS 256

// ---- bucketed counting-sort parameters ----
#define NPB 4096          // nodes per bucket (dst range per bucket)
#define NBK_MAX 1024      // LDS sizing cap for bucket count
#define EBT 8192          // edges per scatter tile
#define CAP 11776         // per-bucket LDS srt capacity (mean 8192, +40 sigma)

// ---------------- utility ----------------

__global__ void k_zero_i(int* __restrict__ p, int n) {
  int i = blockIdx.x * BS + threadIdx.x;
  if (i < n) p[i] = 0;
}

// ---------------- bucketed sort: pass A — global bucket histogram ----------------

__global__ __launch_bounds__(BS) void k_bhist(const int* __restrict__ ei,
                                              int* __restrict__ gh, int M, int NBK) {
  __shared__ int hist[NBK_MAX];
  for (int b = threadIdx.x; b < NBK; b += BS) hist[b] = 0;
  __syncthreads();
  int e0 = blockIdx.x * EBT;
  int n = min(EBT, M - e0);
  for (int k = threadIdx.x; k < n; k += BS) {
    int d = ei[M + e0 + k];
    atomicAdd(&hist[d / NPB], 1);
  }
  __syncthreads();
  for (int b = threadIdx.x; b < NBK; b += BS)
    if (hist[b]) atomicAdd(&gh[b], hist[b]);
}

// ---------------- pass B — single-block scan of bucket sizes ----------------

__global__ __launch_bounds__(BS) void k_bscan(const int* __restrict__ gh,
                                              int* __restrict__ gboff,
                                              int* __restrict__ gcur, int NBK) {
  __shared__ int part[BS];
  int C = (NBK + BS - 1) / BS;
  int s = 0;
  for (int k = 0; k < C; ++k) {
    int idx = threadIdx.x * C + k;
    if (idx < NBK) s += gh[idx];
  }
  part[threadIdx.x] = s;
  __syncthreads();
  for (int off = 1; off < BS; off <<= 1) {
    int v = part[threadIdx.x];
    int u = (threadIdx.x >= off) ? part[threadIdx.x - off] : 0;
    __syncthreads();
    part[threadIdx.x] = v + u;
    __syncthreads();
  }
  int run = (threadIdx.x > 0) ? part[threadIdx.x - 1] : 0;
  for (int k = 0; k < C; ++k) {
    int idx = threadIdx.x * C + k;
    if (idx < NBK) {
      gboff[idx] = run;
      gcur[idx] = run;
      run += gh[idx];
    }
  }
  if (threadIdx.x == BS - 1) gboff[NBK] = run;  // == M
}

// ---------------- pass C — tiled scatter of (src,dst) pairs into bucket runs ----------------

__global__ __launch_bounds__(BS) void k_bscatter(const int* __restrict__ ei,
                                                 int* __restrict__ gcur,
                                                 int2* __restrict__ P, int M, int NBK) {
  __shared__ int hist[NBK_MAX];
  __shared__ int excl[NBK_MAX];
  __shared__ int curs[NBK_MAX];
  __shared__ int base[NBK_MAX];
  __shared__ int part[BS];
  for (int b = threadIdx.x; b < NBK; b += BS) hist[b] = 0;
  __syncthreads();
  int e0 = blockIdx.x * EBT;
  int n = min(EBT, M - e0);
  for (int k = threadIdx.x; k < n; k += BS) {
    int d = ei[M + e0 + k];
    atomicAdd(&hist[d / NPB], 1);
  }
  __syncthreads();
  int C = (NBK + BS - 1) / BS;
  int s = 0;
  for (int k = 0; k < C; ++k) {
    int idx = threadIdx.x * C + k;
    if (idx < NBK) s += hist[idx];
  }
  part[threadIdx.x] = s;
  __syncthreads();
  for (int off = 1; off < BS; off <<= 1) {
    int v = part[threadIdx.x];
    int u = (threadIdx.x >= off) ? part[threadIdx.x - off] : 0;
    __syncthreads();
    part[threadIdx.x] = v + u;
    __syncthreads();
  }
  int run = (threadIdx.x > 0) ? part[threadIdx.x - 1] : 0;
  for (int k = 0; k < C; ++k) {
    int idx = threadIdx.x * C + k;
    if (idx < NBK) {
      excl[idx] = run;
      curs[idx] = run;
      run += hist[idx];
    }
  }
  __syncthreads();
  for (int b = threadIdx.x; b < NBK; b += BS)
    base[b] = hist[b] ? atomicAdd(&gcur[b], hist[b]) : 0;
  __syncthreads();
  for (int k = threadIdx.x; k < n; k += BS) {
    int sidx = ei[e0 + k];
    int d = ei[M + e0 + k];
    int b = d / NPB;
    int pos = atomicAdd(&curs[b], 1);
    int gpos = base[b] + (pos - excl[b]);
    P[gpos] = make_int2(sidx, d);
  }
}

// ---------------- pass D — per-bucket LDS counting sort -> row_ptr + srt ----------------

__global__ __launch_bounds__(BS) void k_bfinal(const int2* __restrict__ P,
                                               const int* __restrict__ gboff,
                                               int* __restrict__ row_ptr,
                                               int* __restrict__ srt, int T, int M,
                                               int NBK) {
  __shared__ int cnt[NPB];
  __shared__ int lsrt[CAP];
  __shared__ int part[BS];
  int b = blockIdx.x;
  int d0 = b * NPB;
  int nodesHere = min(NPB, T - d0);
  int p0 = gboff[b], p1 = gboff[b + 1];
  int nE = p1 - p0;
  for (int j = threadIdx.x; j < NPB; j += BS) cnt[j] = 0;
  __syncthreads();
  for (int j = threadIdx.x; j < nE; j += BS) {
    int2 p = P[p0 + j];
    atomicAdd(&cnt[p.y - d0], 1);
  }
  __syncthreads();
  const int CN = NPB / BS;  // 16
  int s = 0;
#pragma unroll
  for (int k = 0; k < CN; ++k) s += cnt[threadIdx.x * CN + k];
  part[threadIdx.x] = s;
  __syncthreads();
  for (int off = 1; off < BS; off <<= 1) {
    int v = part[threadIdx.x];
    int u = (threadIdx.x >= off) ? part[threadIdx.x - off] : 0;
    __syncthreads();
    part[threadIdx.x] = v + u;
    __syncthreads();
  }
  int run = (threadIdx.x > 0) ? part[threadIdx.x - 1] : 0;
#pragma unroll
  for (int k = 0; k < CN; ++k) {
    int idx = threadIdx.x * CN + k;
    int c = cnt[idx];
    cnt[idx] = run;
    if (idx < nodesHere) row_ptr[d0 + idx] = p0 + run;
    run += c;
  }
  if (b == NBK - 1 && threadIdx.x == 0) row_ptr[T] = M;
  __syncthreads();
  if (nE <= CAP) {
    for (int j = threadIdx.x; j < nE; j += BS) {
      int2 p = P[p0 + j];
      int pos = atomicAdd(&cnt[p.y - d0], 1);
      lsrt[pos] = p.x;
    }
    __syncthreads();
    for (int j = threadIdx.x; j < nE; j += BS) srt[p0 + j] = lsrt[j];
  } else {
    for (int j = threadIdx.x; j < nE; j += BS) {
      int2 p = P[p0 + j];
      int pos = atomicAdd(&cnt[p.y - d0], 1);
      srt[p0 + pos] = p.x;
    }
  }
}

// ---------------- math kernels ----------------

// msg[e] = ec[e]/cnt[e]; oec[e] = (cnt>0) ? 0 : ec  (one pass over E)
__global__ void k_prep_e(const float* __restrict__ ec, const float* __restrict__ cnt,
                         float* __restrict__ msg, float* __restrict__ oec, int E) {
  int i = blockIdx.x * BS + threadIdx.x;
  if (i >= E) return;
  float c = cnt[i], v = ec[i];
  msg[i] = v / c;
  oec[i] = (c > 0.0f) ? 0.0f : v;
}

// step 1: tri4[i] = (t12 + msg[c12], t13 + msg[c13], t23 + msg[c23], dis_i)
__global__ void k_step1pack(const float* __restrict__ msg,
                            const float* __restrict__ t12, const float* __restrict__ t13,
                            const float* __restrict__ t23,
                            const int* __restrict__ c12, const int* __restrict__ c13,
                            const int* __restrict__ c23,
                            const int* __restrict__ row_ptr,
                            float4* __restrict__ tri4, int T) {
  int i = blockIdx.x * BS + threadIdx.x;
  if (i >= T) return;
  int a = c12[i], b = c13[i], c = c23[i];
  float4 v;
  v.x = t12[i] + msg[a];
  v.y = t13[i] + msg[b];
  v.z = t23[i] + msg[c];
  v.w = rsqrtf((float)(row_ptr[i + 1] - row_ptr[i]) + 1.0f);
  tri4[i] = v;
}

// ---- fused layer-1 aggregate + h1 + dis-scale -> H1 (fp16 rows, 64B) ----
// G[i] = tri4[i]*d2 + sum_e tri4[src]*(dis_src*di)   (3ch, in regs)
// H1[i][h] = relu(G[i] @ W1 + b1)[h] * di   (the dis_src factor every consumer needs)
__global__ __launch_bounds__(BS) void k_agg1h1(const int* __restrict__ row_ptr,
                                               const int* __restrict__ srt,
                                               const float4* __restrict__ tri4,
                                               uint* __restrict__ H1u,
                                               const float* __restrict__ W1,
                                               const float* __restrict__ b1, int T) {
  int i = blockIdx.x * BS + threadIdx.x;
  if (i >= T) return;
  int r0 = row_ptr[i], r1 = row_ptr[i + 1];
  float4 ts = tri4[i];
  float di = ts.w;
  float d2 = di * di;
  float ax = ts.x * d2, ay = ts.y * d2, az = ts.z * d2;
  for (int e = r0; e < r1; ++e) {
    float4 v = tri4[srt[e]];            // random 16B, tri4 (32MB) is L2/L3-resident
    float w = v.w * di;
    ax = fmaf(v.x, w, ax);
    ay = fmaf(v.y, w, ay);
    az = fmaf(v.z, w, az);
  }
  uint pk[16];
#pragma unroll
  for (int k = 0; k < 16; ++k) {
    int h = 2 * k;
    float va = fmaf(ax, W1[h], fmaf(ay, W1[HID + h], fmaf(az, W1[2 * HID + h], b1[h])));
    float vb = fmaf(ax, W1[h + 1],
                    fmaf(ay, W1[HID + h + 1], fmaf(az, W1[2 * HID + h + 1], b1[h + 1])));
    va = fmaxf(va, 0.0f) * di;
    vb = fmaxf(vb, 0.0f) * di;
    __half2 p = __floats2half2_rn(va, vb);
    pk[k] = __builtin_bit_cast(uint, p);
  }
  uint4* dst = (uint4*)(H1u + (size_t)i * 16);
  dst[0] = make_uint4(pk[0], pk[1], pk[2], pk[3]);
  dst[1] = make_uint4(pk[4], pk[5], pk[6], pk[7]);
  dst[2] = make_uint4(pk[8], pk[9], pk[10], pk[11]);
  dst[3] = make_uint4(pk[12], pk[13], pk[14], pk[15]);
}

// fp16 row unpack helpers: 8 channels per uint4
__device__ __forceinline__ void h1_init8(const uint4 q, float* S) {
  __half2 a = __builtin_bit_cast(__half2, q.x);
  __half2 b = __builtin_bit_cast(__half2, q.y);
  __half2 c = __builtin_bit_cast(__half2, q.z);
  __half2 d = __builtin_bit_cast(__half2, q.w);
  S[0] = __low2float(a);  S[1] = __high2float(a);
  S[2] = __low2float(b);  S[3] = __high2float(b);
  S[4] = __low2float(c);  S[5] = __high2float(c);
  S[6] = __low2float(d);  S[7] = __high2float(d);
}
__device__ __forceinline__ void h1_acc8(const uint4 q, float* S) {
  __half2 a = __builtin_bit_cast(__half2, q.x);
  __half2 b = __builtin_bit_cast(__half2, q.y);
  __half2 c = __builtin_bit_cast(__half2, q.z);
  __half2 d = __builtin_bit_cast(__half2, q.w);
  // fmaf(cvt(h),1,S) form: lets ISel fold the f16->f32 extend into v_fma_mix
  S[0] = fmaf(__low2float(a), 1.0f, S[0]);
  S[1] = fmaf(__high2float(a), 1.0f, S[1]);
  S[2] = fmaf(__low2float(b), 1.0f, S[2]);
  S[3] = fmaf(__high2float(b), 1.0f, S[3]);
  S[4] = fmaf(__low2float(c), 1.0f, S[4]);
  S[5] = fmaf(__high2float(c), 1.0f, S[5]);
  S[6] = fmaf(__low2float(d), 1.0f, S[6]);
  S[7] = fmaf(__high2float(d), 1.0f, S[7]);
}

// fused layer2 aggregate + W2 + head + scatter.
// acc = di * (H1[i] + sum_e H1[src_e]); z = acc@W2 + b2; delta = relu(z)@Wout + bout.
// No W1/b1 here at all -> edge loop is pure loads+adds (no per-edge 3->32 expand,
// no 128-scalar SGPR working set).
__global__ __launch_bounds__(BS, 4) void k_l2head(
    const int* __restrict__ row_ptr, const int* __restrict__ srt,
    const uint* __restrict__ H1u, const float4* __restrict__ tri4,
    const float* __restrict__ W2, const float* __restrict__ b2,
    const float* __restrict__ Wout, const float* __restrict__ bout,
    const int* __restrict__ c12, const int* __restrict__ c13,
    const int* __restrict__ c23,
    float* __restrict__ o12, float* __restrict__ o13, float* __restrict__ o23,
    float* __restrict__ oec, int T) {
  int i = blockIdx.x * BS + threadIdx.x;
  if (i >= T) return;
  int r0 = row_ptr[i], r1 = row_ptr[i + 1];
  float4 tp = tri4[i];      // hoisted: .xyz for outputs, .w = di
  float S[HID];
  {
    const uint4* hp = (const uint4*)(H1u + (size_t)i * 16);
    uint4 q0 = hp[0], q1 = hp[1], q2 = hp[2], q3 = hp[3];
    h1_init8(q0, S);
    h1_init8(q1, S + 8);
    h1_init8(q2, S + 16);
    h1_init8(q3, S + 24);
  }
  for (int e = r0; e < r1; ++e) {
    int s = srt[e];
    const uint4* hp = (const uint4*)(H1u + (size_t)s * 16);
    uint4 q0 = hp[0], q1 = hp[1], q2 = hp[2], q3 = hp[3];
    h1_acc8(q0, S);
    h1_acc8(q1, S + 8);
    h1_acc8(q2, S + 16);
    h1_acc8(q3, S + 24);
  }
  float di = tp.w;
#pragma unroll
  for (int h = 0; h < HID; ++h) S[h] *= di;

  // z = S @ W2 + b2 in 4 chunks of 8; head folded per chunk.
  float d0 = bout[0], d1 = bout[1], dd2 = bout[2];
#pragma unroll
  for (int cz = 0; cz < HID / 8; ++cz) {
    float z[8];
#pragma unroll
    for (int j = 0; j < 8; ++j) z[j] = b2[cz * 8 + j];
#pragma unroll
    for (int h = 0; h < HID; ++h) {
      float a = S[h];
#pragma unroll
      for (int j = 0; j < 8; ++j) z[j] = fmaf(a, W2[h * HID + cz * 8 + j], z[j]);
    }
#pragma unroll
    for (int j = 0; j < 8; ++j) {
      float v = fmaxf(z[j], 0.0f);
      int hp = cz * 8 + j;
      d0 = fmaf(v, Wout[hp * 3 + 0], d0);
      d1 = fmaf(v, Wout[hp * 3 + 1], d1);
      dd2 = fmaf(v, Wout[hp * 3 + 2], dd2);
    }
  }

  o12[i] = tp.x - d0;
  o13[i] = tp.y - d1;
  o23[i] = tp.z - dd2;
  unsafeAtomicAdd(&oec[c12[i]], d0);
  unsafeAtomicAdd(&oec[c13[i]], d1);
  unsafeAtomicAdd(&oec[c23[i]], dd2);
}

// ---------------- launch ----------------

extern "C" void kernel_launch(void* const* d_in, const int* in_sizes, int n_in,
                              void* d_out, int out_size, void* d_ws, size_t ws_size,
                              hipStream_t stream) {
  const float* ec  = (const float*)d_in[0];
  const float* t12 = (const float*)d_in[1];
  const float* t13 = (const float*)d_in[2];
  const float* t23 = (const float*)d_in[3];
  const int* c12   = (const int*)d_in[4];
  const int* c13   = (const int*)d_in[5];
  const int* c23   = (const int*)d_in[6];
  const float* cnt = (const float*)d_in[7];
  const int* ei    = (const int*)d_in[8];
  const float* W1  = (const float*)d_in[9];
  const float* b1  = (const float*)d_in[10];
  const float* W2  = (const float*)d_in[11];
  const float* b2  = (const float*)d_in[12];
  const float* Wout = (const float*)d_in[13];
  const float* bout = (const float*)d_in[14];

  const int E = in_sizes[0];
  const int T = in_sizes[1];
  const int M = in_sizes[8] / 2;
  const int NBK = (T + NPB - 1) / NPB;  // 512 for T=2M

  float* oec = (float*)d_out;
  float* o12 = oec + E;
  float* o13 = o12 + T;
  float* o23 = o13 + T;

  // workspace (~184 MB):
  // H1u (fp16 rows, T*64B = 128MB) | tri4[16B*T] | srt[M] | rptr[T+1] | gh | gboff | gcur
  // P (int2*M = 32MB) aliases H1u (dead after k_bfinal, H1 written in k_agg1h1).
  // msg (E floats = 4MB) also aliases H1u (written k_prep_e, dead after k_step1pack).
  uint*   H1u  = (uint*)d_ws;                    // T*16 uints = 128MB
  float4* tri4 = (float4*)(H1u + (size_t)T * 16);
  int*    srt  = (int*)(tri4 + T);
  int*    rptr = srt + M;
  int*    gh   = rptr + (T + 1);
  int*    gboff = gh + NBK;
  int*    gcur  = gboff + (NBK + 1);
  int2*   P    = (int2*)H1u;   // alias: dead before H1 written
  float*  msg  = (float*)H1u;  // alias: live only between k_prep_e and k_step1pack

  auto blocks = [](long n) { return (int)((n + BS - 1) / BS); };
  const int tiles = (M + EBT - 1) / EBT;

  // bucketed counting sort by dst -> row_ptr + srt
  k_zero_i<<<blocks(NBK), BS, 0, stream>>>(gh, NBK);
  k_bhist<<<tiles, BS, 0, stream>>>(ei, gh, M, NBK);
  k_bscan<<<1, BS, 0, stream>>>(gh, gboff, gcur, NBK);
  k_bscatter<<<tiles, BS, 0, stream>>>(ei, gcur, P, M, NBK);
  k_bfinal<<<NBK, BS, 0, stream>>>(P, gboff, rptr, srt, T, M, NBK);

  // per-edge prep (msg + output edge-cost init), then step-1 pack
  k_prep_e<<<blocks(E), BS, 0, stream>>>(ec, cnt, msg, oec, E);
  k_step1pack<<<blocks(T), BS, 0, stream>>>(msg, t12, t13, t23, c12, c13, c23,
                                            rptr, tri4, T);

  // layer 1 aggregate fused with h1 + dis scale -> fp16 H1 rows
  k_agg1h1<<<blocks(T), BS, 0, stream>>>(rptr, srt, tri4, H1u, W1, b1, T);

  // layer 2: direct CSR gather of H1 rows + W2 + head + scatter
  k_l2head<<<blocks(T), BS, 0, stream>>>(rptr, srt, H1u, tri4,
                                         W2, b2, Wout, bout,
                                         c12, c13, c23, o12, o13, o23, oec, T);
}

// Round 2
// 794.541 us; speedup vs baseline: 1.0698x; 1.0114x over previous
//
#include <hip/hip_runtime.h>
#include <hip/hip_fp16.h>
#include <math.h>

#define HID 32
#define BS 256

// ---- bucketed counting-sort parameters ----
#define NPB 4096          // nodes per bucket (dst range per bucket)
#define NBK_MAX 1024      // LDS sizing cap for bucket count
#define EBT 8192          // edges per scatter tile
#define CAP 11776         // per-bucket LDS srt capacity (mean 8192, +40 sigma)

// ---------------- utility ----------------

__global__ void k_zero_i(int* __restrict__ p, int n) {
  int i = blockIdx.x * BS + threadIdx.x;
  if (i < n) p[i] = 0;
}

// ---------------- bucketed sort: pass A — global bucket histogram ----------------

__global__ __launch_bounds__(BS) void k_bhist(const int* __restrict__ ei,
                                              int* __restrict__ gh, int M, int NBK) {
  __shared__ int hist[NBK_MAX];
  for (int b = threadIdx.x; b < NBK; b += BS) hist[b] = 0;
  __syncthreads();
  int e0 = blockIdx.x * EBT;
  int n = min(EBT, M - e0);
  for (int k = threadIdx.x; k < n; k += BS) {
    int d = ei[M + e0 + k];
    atomicAdd(&hist[d / NPB], 1);
  }
  __syncthreads();
  for (int b = threadIdx.x; b < NBK; b += BS)
    if (hist[b]) atomicAdd(&gh[b], hist[b]);
}

// ---------------- pass B — single-block scan of bucket sizes ----------------

__global__ __launch_bounds__(BS) void k_bscan(const int* __restrict__ gh,
                                              int* __restrict__ gboff,
                                              int* __restrict__ gcur, int NBK) {
  __shared__ int part[BS];
  int C = (NBK + BS - 1) / BS;
  int s = 0;
  for (int k = 0; k < C; ++k) {
    int idx = threadIdx.x * C + k;
    if (idx < NBK) s += gh[idx];
  }
  part[threadIdx.x] = s;
  __syncthreads();
  for (int off = 1; off < BS; off <<= 1) {
    int v = part[threadIdx.x];
    int u = (threadIdx.x >= off) ? part[threadIdx.x - off] : 0;
    __syncthreads();
    part[threadIdx.x] = v + u;
    __syncthreads();
  }
  int run = (threadIdx.x > 0) ? part[threadIdx.x - 1] : 0;
  for (int k = 0; k < C; ++k) {
    int idx = threadIdx.x * C + k;
    if (idx < NBK) {
      gboff[idx] = run;
      gcur[idx] = run;
      run += gh[idx];
    }
  }
  if (threadIdx.x == BS - 1) gboff[NBK] = run;  // == M
}

// ---------------- pass C — tiled scatter of (src,dst) pairs into bucket runs ----------------

__global__ __launch_bounds__(BS) void k_bscatter(const int* __restrict__ ei,
                                                 int* __restrict__ gcur,
                                                 int2* __restrict__ P, int M, int NBK) {
  __shared__ int hist[NBK_MAX];
  __shared__ int excl[NBK_MAX];
  __shared__ int curs[NBK_MAX];
  __shared__ int base[NBK_MAX];
  __shared__ int part[BS];
  for (int b = threadIdx.x; b < NBK; b += BS) hist[b] = 0;
  __syncthreads();
  int e0 = blockIdx.x * EBT;
  int n = min(EBT, M - e0);
  for (int k = threadIdx.x; k < n; k += BS) {
    int d = ei[M + e0 + k];
    atomicAdd(&hist[d / NPB], 1);
  }
  __syncthreads();
  int C = (NBK + BS - 1) / BS;
  int s = 0;
  for (int k = 0; k < C; ++k) {
    int idx = threadIdx.x * C + k;
    if (idx < NBK) s += hist[idx];
  }
  part[threadIdx.x] = s;
  __syncthreads();
  for (int off = 1; off < BS; off <<= 1) {
    int v = part[threadIdx.x];
    int u = (threadIdx.x >= off) ? part[threadIdx.x - off] : 0;
    __syncthreads();
    part[threadIdx.x] = v + u;
    __syncthreads();
  }
  int run = (threadIdx.x > 0) ? part[threadIdx.x - 1] : 0;
  for (int k = 0; k < C; ++k) {
    int idx = threadIdx.x * C + k;
    if (idx < NBK) {
      excl[idx] = run;
      curs[idx] = run;
      run += hist[idx];
    }
  }
  __syncthreads();
  for (int b = threadIdx.x; b < NBK; b += BS)
    base[b] = hist[b] ? atomicAdd(&gcur[b], hist[b]) : 0;
  __syncthreads();
  for (int k = threadIdx.x; k < n; k += BS) {
    int sidx = ei[e0 + k];
    int d = ei[M + e0 + k];
    int b = d / NPB;
    int pos = atomicAdd(&curs[b], 1);
    int gpos = base[b] + (pos - excl[b]);
    P[gpos] = make_int2(sidx, d);
  }
}

// ---------------- pass D — per-bucket LDS counting sort -> row_ptr + srt ----------------

__global__ __launch_bounds__(BS) void k_bfinal(const int2* __restrict__ P,
                                               const int* __restrict__ gboff,
                                               int* __restrict__ row_ptr,
                                               int* __restrict__ srt, int T, int M,
                                               int NBK) {
  __shared__ int cnt[NPB];
  __shared__ int lsrt[CAP];
  __shared__ int part[BS];
  int b = blockIdx.x;
  int d0 = b * NPB;
  int nodesHere = min(NPB, T - d0);
  int p0 = gboff[b], p1 = gboff[b + 1];
  int nE = p1 - p0;
  for (int j = threadIdx.x; j < NPB; j += BS) cnt[j] = 0;
  __syncthreads();
  for (int j = threadIdx.x; j < nE; j += BS) {
    int2 p = P[p0 + j];
    atomicAdd(&cnt[p.y - d0], 1);
  }
  __syncthreads();
  const int CN = NPB / BS;  // 16
  int s = 0;
#pragma unroll
  for (int k = 0; k < CN; ++k) s += cnt[threadIdx.x * CN + k];
  part[threadIdx.x] = s;
  __syncthreads();
  for (int off = 1; off < BS; off <<= 1) {
    int v = part[threadIdx.x];
    int u = (threadIdx.x >= off) ? part[threadIdx.x - off] : 0;
    __syncthreads();
    part[threadIdx.x] = v + u;
    __syncthreads();
  }
  int run = (threadIdx.x > 0) ? part[threadIdx.x - 1] : 0;
#pragma unroll
  for (int k = 0; k < CN; ++k) {
    int idx = threadIdx.x * CN + k;
    int c = cnt[idx];
    cnt[idx] = run;
    if (idx < nodesHere) row_ptr[d0 + idx] = p0 + run;
    run += c;
  }
  if (b == NBK - 1 && threadIdx.x == 0) row_ptr[T] = M;
  __syncthreads();
  if (nE <= CAP) {
    for (int j = threadIdx.x; j < nE; j += BS) {
      int2 p = P[p0 + j];
      int pos = atomicAdd(&cnt[p.y - d0], 1);
      lsrt[pos] = p.x;
    }
    __syncthreads();
    for (int j = threadIdx.x; j < nE; j += BS) srt[p0 + j] = lsrt[j];
  } else {
    for (int j = threadIdx.x; j < nE; j += BS) {
      int2 p = P[p0 + j];
      int pos = atomicAdd(&cnt[p.y - d0], 1);
      srt[p0 + pos] = p.x;
    }
  }
}

// ---------------- math kernels ----------------

// msg[e] = ec[e]/cnt[e]; oec[e] = (cnt>0) ? 0 : ec  (one pass over E)
__global__ void k_prep_e(const float* __restrict__ ec, const float* __restrict__ cnt,
                         float* __restrict__ msg, float* __restrict__ oec, int E) {
  int i = blockIdx.x * BS + threadIdx.x;
  if (i >= E) return;
  float c = cnt[i], v = ec[i];
  msg[i] = v / c;
  oec[i] = (c > 0.0f) ? 0.0f : v;
}

// step 1: tri4[i] = (t12 + msg[c12], t13 + msg[c13], t23 + msg[c23], dis_i)
__global__ void k_step1pack(const float* __restrict__ msg,
                            const float* __restrict__ t12, const float* __restrict__ t13,
                            const float* __restrict__ t23,
                            const int* __restrict__ c12, const int* __restrict__ c13,
                            const int* __restrict__ c23,
                            const int* __restrict__ row_ptr,
                            float4* __restrict__ tri4, int T) {
  int i = blockIdx.x * BS + threadIdx.x;
  if (i >= T) return;
  int a = c12[i], b = c13[i], c = c23[i];
  float4 v;
  v.x = t12[i] + msg[a];
  v.y = t13[i] + msg[b];
  v.z = t23[i] + msg[c];
  v.w = rsqrtf((float)(row_ptr[i + 1] - row_ptr[i]) + 1.0f);
  tri4[i] = v;
}

// ---- fused layer-1 aggregate + h1 + dis-scale -> H1 (fp16 rows, 64B) ----
__global__ __launch_bounds__(BS) void k_agg1h1(const int* __restrict__ row_ptr,
                                               const int* __restrict__ srt,
                                               const float4* __restrict__ tri4,
                                               uint* __restrict__ H1u,
                                               const float* __restrict__ W1,
                                               const float* __restrict__ b1, int T) {
  int i = blockIdx.x * BS + threadIdx.x;
  if (i >= T) return;
  int r0 = row_ptr[i], r1 = row_ptr[i + 1];
  float4 ts = tri4[i];
  float di = ts.w;
  float d2 = di * di;
  float ax = ts.x * d2, ay = ts.y * d2, az = ts.z * d2;
  for (int e = r0; e < r1; ++e) {
    float4 v = tri4[srt[e]];            // random 16B, tri4 (32MB) is L2/L3-resident
    float w = v.w * di;
    ax = fmaf(v.x, w, ax);
    ay = fmaf(v.y, w, ay);
    az = fmaf(v.z, w, az);
  }
  uint pk[16];
#pragma unroll
  for (int k = 0; k < 16; ++k) {
    int h = 2 * k;
    float va = fmaf(ax, W1[h], fmaf(ay, W1[HID + h], fmaf(az, W1[2 * HID + h], b1[h])));
    float vb = fmaf(ax, W1[h + 1],
                    fmaf(ay, W1[HID + h + 1], fmaf(az, W1[2 * HID + h + 1], b1[h + 1])));
    va = fmaxf(va, 0.0f) * di;
    vb = fmaxf(vb, 0.0f) * di;
    __half2 p = __floats2half2_rn(va, vb);
    pk[k] = __builtin_bit_cast(uint, p);
  }
  uint4* dst = (uint4*)(H1u + (size_t)i * 16);
  dst[0] = make_uint4(pk[0], pk[1], pk[2], pk[3]);
  dst[1] = make_uint4(pk[4], pk[5], pk[6], pk[7]);
  dst[2] = make_uint4(pk[8], pk[9], pk[10], pk[11]);
  dst[3] = make_uint4(pk[12], pk[13], pk[14], pk[15]);
}

// fp16 row unpack helpers: 8 channels per uint4
__device__ __forceinline__ void h1_init8(const uint4 q, float* S) {
  __half2 a = __builtin_bit_cast(__half2, q.x);
  __half2 b = __builtin_bit_cast(__half2, q.y);
  __half2 c = __builtin_bit_cast(__half2, q.z);
  __half2 d = __builtin_bit_cast(__half2, q.w);
  S[0] = __low2float(a);  S[1] = __high2float(a);
  S[2] = __low2float(b);  S[3] = __high2float(b);
  S[4] = __low2float(c);  S[5] = __high2float(c);
  S[6] = __low2float(d);  S[7] = __high2float(d);
}
__device__ __forceinline__ void h1_acc8(const uint4 q, float* S) {
  __half2 a = __builtin_bit_cast(__half2, q.x);
  __half2 b = __builtin_bit_cast(__half2, q.y);
  __half2 c = __builtin_bit_cast(__half2, q.z);
  __half2 d = __builtin_bit_cast(__half2, q.w);
  S[0] = fmaf(__low2float(a), 1.0f, S[0]);
  S[1] = fmaf(__high2float(a), 1.0f, S[1]);
  S[2] = fmaf(__low2float(b), 1.0f, S[2]);
  S[3] = fmaf(__high2float(b), 1.0f, S[3]);
  S[4] = fmaf(__low2float(c), 1.0f, S[4]);
  S[5] = fmaf(__high2float(c), 1.0f, S[5]);
  S[6] = fmaf(__low2float(d), 1.0f, S[6]);
  S[7] = fmaf(__high2float(d), 1.0f, S[7]);
}

// fused layer2 aggregate + W2 + head + scatter.
// acc = di * (H1[i] + sum_e H1[src_e]); z = acc@W2 + b2; delta = relu(z)@Wout + bout.
// Latency-bound on the random 64B H1-row gather (R1: FETCH 347MB @ 1.5TB/s,
// VALUBusy 47%) -> needs wave concurrency, not VGPR budget. The old (BS,4)
// cap (16 waves/CU, inherited from the W1-heavy version that needed 128 VGPR)
// is removed: (BS,8) permits 32 waves/CU; kernel uses 44 VGPR <= the 64 cap.
__global__ __launch_bounds__(BS, 8) void k_l2head(
    const int* __restrict__ row_ptr, const int* __restrict__ srt,
    const uint* __restrict__ H1u, const float4* __restrict__ tri4,
    const float* __restrict__ W2, const float* __restrict__ b2,
    const float* __restrict__ Wout, const float* __restrict__ bout,
    const int* __restrict__ c12, const int* __restrict__ c13,
    const int* __restrict__ c23,
    float* __restrict__ o12, float* __restrict__ o13, float* __restrict__ o23,
    float* __restrict__ oec, int T) {
  int i = blockIdx.x * BS + threadIdx.x;
  if (i >= T) return;
  int r0 = row_ptr[i], r1 = row_ptr[i + 1];
  float4 tp = tri4[i];      // hoisted: .xyz for outputs, .w = di
  float S[HID];
  {
    const uint4* hp = (const uint4*)(H1u + (size_t)i * 16);
    uint4 q0 = hp[0], q1 = hp[1], q2 = hp[2], q3 = hp[3];
    h1_init8(q0, S);
    h1_init8(q1, S + 8);
    h1_init8(q2, S + 16);
    h1_init8(q3, S + 24);
  }
  for (int e = r0; e < r1; ++e) {
    int s = srt[e];
    const uint4* hp = (const uint4*)(H1u + (size_t)s * 16);
    uint4 q0 = hp[0], q1 = hp[1], q2 = hp[2], q3 = hp[3];
    h1_acc8(q0, S);
    h1_acc8(q1, S + 8);
    h1_acc8(q2, S + 16);
    h1_acc8(q3, S + 24);
  }
  float di = tp.w;
#pragma unroll
  for (int h = 0; h < HID; ++h) S[h] *= di;

  // z = S @ W2 + b2 in 4 chunks of 8; head folded per chunk.
  float d0 = bout[0], d1 = bout[1], dd2 = bout[2];
#pragma unroll
  for (int cz = 0; cz < HID / 8; ++cz) {
    float z[8];
#pragma unroll
    for (int j = 0; j < 8; ++j) z[j] = b2[cz * 8 + j];
#pragma unroll
    for (int h = 0; h < HID; ++h) {
      float a = S[h];
#pragma unroll
      for (int j = 0; j < 8; ++j) z[j] = fmaf(a, W2[h * HID + cz * 8 + j], z[j]);
    }
#pragma unroll
    for (int j = 0; j < 8; ++j) {
      float v = fmaxf(z[j], 0.0f);
      int hp = cz * 8 + j;
      d0 = fmaf(v, Wout[hp * 3 + 0], d0);
      d1 = fmaf(v, Wout[hp * 3 + 1], d1);
      dd2 = fmaf(v, Wout[hp * 3 + 2], dd2);
    }
  }

  o12[i] = tp.x - d0;
  o13[i] = tp.y - d1;
  o23[i] = tp.z - dd2;
  unsafeAtomicAdd(&oec[c12[i]], d0);
  unsafeAtomicAdd(&oec[c13[i]], d1);
  unsafeAtomicAdd(&oec[c23[i]], dd2);
}

// ---------------- launch ----------------

extern "C" void kernel_launch(void* const* d_in, const int* in_sizes, int n_in,
                              void* d_out, int out_size, void* d_ws, size_t ws_size,
                              hipStream_t stream) {
  const float* ec  = (const float*)d_in[0];
  const float* t12 = (const float*)d_in[1];
  const float* t13 = (const float*)d_in[2];
  const float* t23 = (const float*)d_in[3];
  const int* c12   = (const int*)d_in[4];
  const int* c13   = (const int*)d_in[5];
  const int* c23   = (const int*)d_in[6];
  const float* cnt = (const float*)d_in[7];
  const int* ei    = (const int*)d_in[8];
  const float* W1  = (const float*)d_in[9];
  const float* b1  = (const float*)d_in[10];
  const float* W2  = (const float*)d_in[11];
  const float* b2  = (const float*)d_in[12];
  const float* Wout = (const float*)d_in[13];
  const float* bout = (const float*)d_in[14];

  const int E = in_sizes[0];
  const int T = in_sizes[1];
  const int M = in_sizes[8] / 2;
  const int NBK = (T + NPB - 1) / NPB;  // 512 for T=2M

  float* oec = (float*)d_out;
  float* o12 = oec + E;
  float* o13 = o12 + T;
  float* o23 = o13 + T;

  // workspace (~184 MB):
  // H1u (fp16 rows, T*64B = 128MB) | tri4[16B*T] | srt[M] | rptr[T+1] | gh | gboff | gcur
  // P (int2*M = 32MB) aliases H1u (dead after k_bfinal, H1 written in k_agg1h1).
  // msg (E floats = 4MB) also aliases H1u (written k_prep_e, dead after k_step1pack).
  uint*   H1u  = (uint*)d_ws;                    // T*16 uints = 128MB
  float4* tri4 = (float4*)(H1u + (size_t)T * 16);
  int*    srt  = (int*)(tri4 + T);
  int*    rptr = srt + M;
  int*    gh   = rptr + (T + 1);
  int*    gboff = gh + NBK;
  int*    gcur  = gboff + (NBK + 1);
  int2*   P    = (int2*)H1u;   // alias: dead before H1 written
  float*  msg  = (float*)H1u;  // alias: live only between k_prep_e and k_step1pack

  auto blocks = [](long n) { return (int)((n + BS - 1) / BS); };
  const int tiles = (M + EBT - 1) / EBT;

  // bucketed counting sort by dst -> row_ptr + srt
  k_zero_i<<<blocks(NBK), BS, 0, stream>>>(gh, NBK);
  k_bhist<<<tiles, BS, 0, stream>>>(ei, gh, M, NBK);
  k_bscan<<<1, BS, 0, stream>>>(gh, gboff, gcur, NBK);
  k_bscatter<<<tiles, BS, 0, stream>>>(ei, gcur, P, M, NBK);
  k_bfinal<<<NBK, BS, 0, stream>>>(P, gboff, rptr, srt, T, M, NBK);

  // per-edge prep (msg + output edge-cost init), then step-1 pack
  k_prep_e<<<blocks(E), BS, 0, stream>>>(ec, cnt, msg, oec, E);
  k_step1pack<<<blocks(T), BS, 0, stream>>>(msg, t12, t13, t23, c12, c13, c23,
                                            rptr, tri4, T);

  // layer 1 aggregate fused with h1 + dis scale -> fp16 H1 rows
  k_agg1h1<<<blocks(T), BS, 0, stream>>>(rptr, srt, tri4, H1u, W1, b1, T);

  // layer 2: direct CSR gather of H1 rows + W2 + head + scatter
  k_l2head<<<blocks(T), BS, 0, stream>>>(rptr, srt, H1u, tri4,
                                         W2, b2, Wout, bout,
                                         c12, c13, c23, o12, o13, o23, oec, T);
}

// Round 3
// 784.850 us; speedup vs baseline: 1.0830x; 1.0123x over previous
//
#include <hip/hip_runtime.h>
#include <hip/hip_fp16.h>
#include <math.h>

#define HID 32
#define BS 256

// ---- bucketed counting-sort parameters ----
#define NPB 4096          // nodes per bucket (dst range per bucket)
#define NBK_MAX 1024      // LDS sizing cap for bucket count
#define EBT 8192          // edges per scatter tile
#define CAP 11776         // per-bucket LDS srt capacity (mean 8192, +40 sigma)

// ---- non-temporal helpers (clang builtins need real vector types) ----
typedef float  v4f __attribute__((ext_vector_type(4)));

__device__ __forceinline__ int ntload_i(const int* p) {
  return __builtin_nontemporal_load(p);
}
__device__ __forceinline__ float4 ntload_f4(const float4* p) {
  v4f v = __builtin_nontemporal_load((const v4f*)p);
  float4 r; r.x = v.x; r.y = v.y; r.z = v.z; r.w = v.w; return r;
}
__device__ __forceinline__ void ntstore_f(float v, float* p) {
  __builtin_nontemporal_store(v, p);
}

// ---------------- utility ----------------

__global__ void k_zero_i(int* __restrict__ p, int n) {
  int i = blockIdx.x * BS + threadIdx.x;
  if (i < n) p[i] = 0;
}

// ---------------- bucketed sort: pass A — global bucket histogram ----------------

__global__ __launch_bounds__(BS) void k_bhist(const int* __restrict__ ei,
                                              int* __restrict__ gh, int M, int NBK) {
  __shared__ int hist[NBK_MAX];
  for (int b = threadIdx.x; b < NBK; b += BS) hist[b] = 0;
  __syncthreads();
  int e0 = blockIdx.x * EBT;
  int n = min(EBT, M - e0);
  for (int k = threadIdx.x; k < n; k += BS) {
    int d = ei[M + e0 + k];
    atomicAdd(&hist[d / NPB], 1);
  }
  __syncthreads();
  for (int b = threadIdx.x; b < NBK; b += BS)
    if (hist[b]) atomicAdd(&gh[b], hist[b]);
}

// ---------------- pass B — single-block scan of bucket sizes ----------------

__global__ __launch_bounds__(BS) void k_bscan(const int* __restrict__ gh,
                                              int* __restrict__ gboff,
                                              int* __restrict__ gcur, int NBK) {
  __shared__ int part[BS];
  int C = (NBK + BS - 1) / BS;
  int s = 0;
  for (int k = 0; k < C; ++k) {
    int idx = threadIdx.x * C + k;
    if (idx < NBK) s += gh[idx];
  }
  part[threadIdx.x] = s;
  __syncthreads();
  for (int off = 1; off < BS; off <<= 1) {
    int v = part[threadIdx.x];
    int u = (threadIdx.x >= off) ? part[threadIdx.x - off] : 0;
    __syncthreads();
    part[threadIdx.x] = v + u;
    __syncthreads();
  }
  int run = (threadIdx.x > 0) ? part[threadIdx.x - 1] : 0;
  for (int k = 0; k < C; ++k) {
    int idx = threadIdx.x * C + k;
    if (idx < NBK) {
      gboff[idx] = run;
      gcur[idx] = run;
      run += gh[idx];
    }
  }
  if (threadIdx.x == BS - 1) gboff[NBK] = run;  // == M
}

// ---------------- pass C — tiled scatter of (src,dst) pairs into bucket runs ----------------

__global__ __launch_bounds__(BS) void k_bscatter(const int* __restrict__ ei,
                                                 int* __restrict__ gcur,
                                                 int2* __restrict__ P, int M, int NBK) {
  __shared__ int hist[NBK_MAX];
  __shared__ int excl[NBK_MAX];
  __shared__ int curs[NBK_MAX];
  __shared__ int base[NBK_MAX];
  __shared__ int part[BS];
  for (int b = threadIdx.x; b < NBK; b += BS) hist[b] = 0;
  __syncthreads();
  int e0 = blockIdx.x * EBT;
  int n = min(EBT, M - e0);
  for (int k = threadIdx.x; k < n; k += BS) {
    int d = ei[M + e0 + k];
    atomicAdd(&hist[d / NPB], 1);
  }
  __syncthreads();
  int C = (NBK + BS - 1) / BS;
  int s = 0;
  for (int k = 0; k < C; ++k) {
    int idx = threadIdx.x * C + k;
    if (idx < NBK) s += hist[idx];
  }
  part[threadIdx.x] = s;
  __syncthreads();
  for (int off = 1; off < BS; off <<= 1) {
    int v = part[threadIdx.x];
    int u = (threadIdx.x >= off) ? part[threadIdx.x - off] : 0;
    __syncthreads();
    part[threadIdx.x] = v + u;
    __syncthreads();
  }
  int run = (threadIdx.x > 0) ? part[threadIdx.x - 1] : 0;
  for (int k = 0; k < C; ++k) {
    int idx = threadIdx.x * C + k;
    if (idx < NBK) {
      excl[idx] = run;
      curs[idx] = run;
      run += hist[idx];
    }
  }
  __syncthreads();
  for (int b = threadIdx.x; b < NBK; b += BS)
    base[b] = hist[b] ? atomicAdd(&gcur[b], hist[b]) : 0;
  __syncthreads();
  for (int k = threadIdx.x; k < n; k += BS) {
    int sidx = ei[e0 + k];
    int d = ei[M + e0 + k];
    int b = d / NPB;
    int pos = atomicAdd(&curs[b], 1);
    int gpos = base[b] + (pos - excl[b]);
    P[gpos] = make_int2(sidx, d);
  }
}

// ---------------- pass D — per-bucket LDS counting sort -> row_ptr + srt ----------------

__global__ __launch_bounds__(BS) void k_bfinal(const int2* __restrict__ P,
                                               const int* __restrict__ gboff,
                                               int* __restrict__ row_ptr,
                                               int* __restrict__ srt, int T, int M,
                                               int NBK) {
  __shared__ int cnt[NPB];
  __shared__ int lsrt[CAP];
  __shared__ int part[BS];
  int b = blockIdx.x;
  int d0 = b * NPB;
  int nodesHere = min(NPB, T - d0);
  int p0 = gboff[b], p1 = gboff[b + 1];
  int nE = p1 - p0;
  for (int j = threadIdx.x; j < NPB; j += BS) cnt[j] = 0;
  __syncthreads();
  for (int j = threadIdx.x; j < nE; j += BS) {
    int2 p = P[p0 + j];
    atomicAdd(&cnt[p.y - d0], 1);
  }
  __syncthreads();
  const int CN = NPB / BS;  // 16
  int s = 0;
#pragma unroll
  for (int k = 0; k < CN; ++k) s += cnt[threadIdx.x * CN + k];
  part[threadIdx.x] = s;
  __syncthreads();
  for (int off = 1; off < BS; off <<= 1) {
    int v = part[threadIdx.x];
    int u = (threadIdx.x >= off) ? part[threadIdx.x - off] : 0;
    __syncthreads();
    part[threadIdx.x] = v + u;
    __syncthreads();
  }
  int run = (threadIdx.x > 0) ? part[threadIdx.x - 1] : 0;
#pragma unroll
  for (int k = 0; k < CN; ++k) {
    int idx = threadIdx.x * CN + k;
    int c = cnt[idx];
    cnt[idx] = run;
    if (idx < nodesHere) row_ptr[d0 + idx] = p0 + run;
    run += c;
  }
  if (b == NBK - 1 && threadIdx.x == 0) row_ptr[T] = M;
  __syncthreads();
  if (nE <= CAP) {
    for (int j = threadIdx.x; j < nE; j += BS) {
      int2 p = P[p0 + j];
      int pos = atomicAdd(&cnt[p.y - d0], 1);
      lsrt[pos] = p.x;
    }
    __syncthreads();
    for (int j = threadIdx.x; j < nE; j += BS) srt[p0 + j] = lsrt[j];
  } else {
    for (int j = threadIdx.x; j < nE; j += BS) {
      int2 p = P[p0 + j];
      int pos = atomicAdd(&cnt[p.y - d0], 1);
      srt[p0 + pos] = p.x;
    }
  }
}

// ---------------- math kernels ----------------

// msg[e] = ec[e]/cnt[e]; oec[e] = (cnt>0) ? 0 : ec  (one pass over E)
__global__ void k_prep_e(const float* __restrict__ ec, const float* __restrict__ cnt,
                         float* __restrict__ msg, float* __restrict__ oec, int E) {
  int i = blockIdx.x * BS + threadIdx.x;
  if (i >= E) return;
  float c = cnt[i], v = ec[i];
  msg[i] = v / c;
  oec[i] = (c > 0.0f) ? 0.0f : v;
}

// step 1: tri4[i] = (t12 + msg[c12], t13 + msg[c13], t23 + msg[c23], dis_i)
__global__ void k_step1pack(const float* __restrict__ msg,
                            const float* __restrict__ t12, const float* __restrict__ t13,
                            const float* __restrict__ t23,
                            const int* __restrict__ c12, const int* __restrict__ c13,
                            const int* __restrict__ c23,
                            const int* __restrict__ row_ptr,
                            float4* __restrict__ tri4, int T) {
  int i = blockIdx.x * BS + threadIdx.x;
  if (i >= T) return;
  int a = c12[i], b = c13[i], c = c23[i];
  float4 v;
  v.x = t12[i] + msg[a];
  v.y = t13[i] + msg[b];
  v.z = t23[i] + msg[c];
  v.w = rsqrtf((float)(row_ptr[i + 1] - row_ptr[i]) + 1.0f);
  tri4[i] = v;
}

// ---- fused layer-1 aggregate + h1 + dis-scale -> H1 (fp16 rows, 64B) ----
// Edge loop batched 4-wide: all srt indices + all 4 row loads issued as
// independent locals before any accumulate -> ~4x per-thread MLP on the
// dependent srt->row chain.
__global__ __launch_bounds__(BS) void k_agg1h1(const int* __restrict__ row_ptr,
                                               const int* __restrict__ srt,
                                               const float4* __restrict__ tri4,
                                               uint* __restrict__ H1u,
                                               const float* __restrict__ W1,
                                               const float* __restrict__ b1, int T) {
  int i = blockIdx.x * BS + threadIdx.x;
  if (i >= T) return;
  int r0 = row_ptr[i], r1 = row_ptr[i + 1];
  float4 ts = tri4[i];
  float di = ts.w;
  float d2 = di * di;
  float ax = ts.x * d2, ay = ts.y * d2, az = ts.z * d2;
  int e = r0;
  for (; e + 4 <= r1; e += 4) {
    int s0 = ntload_i(&srt[e + 0]);
    int s1 = ntload_i(&srt[e + 1]);
    int s2 = ntload_i(&srt[e + 2]);
    int s3 = ntload_i(&srt[e + 3]);
    float4 v0 = tri4[s0];
    float4 v1 = tri4[s1];
    float4 v2 = tri4[s2];
    float4 v3 = tri4[s3];
    float w0 = v0.w * di, w1 = v1.w * di, w2 = v2.w * di, w3 = v3.w * di;
    ax = fmaf(v0.x, w0, ax); ay = fmaf(v0.y, w0, ay); az = fmaf(v0.z, w0, az);
    ax = fmaf(v1.x, w1, ax); ay = fmaf(v1.y, w1, ay); az = fmaf(v1.z, w1, az);
    ax = fmaf(v2.x, w2, ax); ay = fmaf(v2.y, w2, ay); az = fmaf(v2.z, w2, az);
    ax = fmaf(v3.x, w3, ax); ay = fmaf(v3.y, w3, ay); az = fmaf(v3.z, w3, az);
  }
  for (; e < r1; ++e) {
    float4 v = tri4[srt[e]];
    float w = v.w * di;
    ax = fmaf(v.x, w, ax);
    ay = fmaf(v.y, w, ay);
    az = fmaf(v.z, w, az);
  }
  uint pk[16];
#pragma unroll
  for (int k = 0; k < 16; ++k) {
    int h = 2 * k;
    float va = fmaf(ax, W1[h], fmaf(ay, W1[HID + h], fmaf(az, W1[2 * HID + h], b1[h])));
    float vb = fmaf(ax, W1[h + 1],
                    fmaf(ay, W1[HID + h + 1], fmaf(az, W1[2 * HID + h + 1], b1[h + 1])));
    va = fmaxf(va, 0.0f) * di;
    vb = fmaxf(vb, 0.0f) * di;
    __half2 p = __floats2half2_rn(va, vb);
    pk[k] = __builtin_bit_cast(uint, p);
  }
  uint4* dst = (uint4*)(H1u + (size_t)i * 16);
  dst[0] = make_uint4(pk[0], pk[1], pk[2], pk[3]);
  dst[1] = make_uint4(pk[4], pk[5], pk[6], pk[7]);
  dst[2] = make_uint4(pk[8], pk[9], pk[10], pk[11]);
  dst[3] = make_uint4(pk[12], pk[13], pk[14], pk[15]);
}

// fp16 row unpack helpers: 8 channels per uint4
__device__ __forceinline__ void h1_init8(const uint4 q, float* S) {
  __half2 a = __builtin_bit_cast(__half2, q.x);
  __half2 b = __builtin_bit_cast(__half2, q.y);
  __half2 c = __builtin_bit_cast(__half2, q.z);
  __half2 d = __builtin_bit_cast(__half2, q.w);
  S[0] = __low2float(a);  S[1] = __high2float(a);
  S[2] = __low2float(b);  S[3] = __high2float(b);
  S[4] = __low2float(c);  S[5] = __high2float(c);
  S[6] = __low2float(d);  S[7] = __high2float(d);
}
__device__ __forceinline__ void h1_acc8(const uint4 q, float* S) {
  __half2 a = __builtin_bit_cast(__half2, q.x);
  __half2 b = __builtin_bit_cast(__half2, q.y);
  __half2 c = __builtin_bit_cast(__half2, q.z);
  __half2 d = __builtin_bit_cast(__half2, q.w);
  S[0] = fmaf(__low2float(a), 1.0f, S[0]);
  S[1] = fmaf(__high2float(a), 1.0f, S[1]);
  S[2] = fmaf(__low2float(b), 1.0f, S[2]);
  S[3] = fmaf(__high2float(b), 1.0f, S[3]);
  S[4] = fmaf(__low2float(c), 1.0f, S[4]);
  S[5] = fmaf(__high2float(c), 1.0f, S[5]);
  S[6] = fmaf(__low2float(d), 1.0f, S[6]);
  S[7] = fmaf(__high2float(d), 1.0f, S[7]);
}

// fused layer2 aggregate + W2 + head + scatter.
// R2 post-mortem: (BS,8) budget=64 forced spills (VGPR 44->32, WRITE +47MB) and
// ate the occupancy gain. (BS,6) budget=85 fits the batched loop (~70 live)
// with 24 waves/CU. Edge loop batched 2-wide: both rows' 8 loads issued as
// independent locals -> ~2x per-thread MLP. One-shot streams (srt, tri4[i],
// c1x, o1x) are non-temporal so they stop evicting the H1 table from L2/L3.
__global__ __launch_bounds__(BS, 6) void k_l2head(
    const int* __restrict__ row_ptr, const int* __restrict__ srt,
    const uint* __restrict__ H1u, const float4* __restrict__ tri4,
    const float* __restrict__ W2, const float* __restrict__ b2,
    const float* __restrict__ Wout, const float* __restrict__ bout,
    const int* __restrict__ c12, const int* __restrict__ c13,
    const int* __restrict__ c23,
    float* __restrict__ o12, float* __restrict__ o13, float* __restrict__ o23,
    float* __restrict__ oec, int T) {
  int i = blockIdx.x * BS + threadIdx.x;
  if (i >= T) return;
  int r0 = row_ptr[i], r1 = row_ptr[i + 1];
  float4 tp = ntload_f4(&tri4[i]);  // one-shot stream: .xyz outputs, .w = di
  float S[HID];
  {
    const uint4* hp = (const uint4*)(H1u + (size_t)i * 16);
    uint4 q0 = hp[0], q1 = hp[1], q2 = hp[2], q3 = hp[3];
    h1_init8(q0, S);
    h1_init8(q1, S + 8);
    h1_init8(q2, S + 16);
    h1_init8(q3, S + 24);
  }
  int e = r0;
  for (; e + 2 <= r1; e += 2) {
    int s0 = ntload_i(&srt[e + 0]);
    int s1 = ntload_i(&srt[e + 1]);
    const uint4* ha = (const uint4*)(H1u + (size_t)s0 * 16);
    const uint4* hb = (const uint4*)(H1u + (size_t)s1 * 16);
    uint4 a0 = ha[0], a1 = ha[1], a2 = ha[2], a3 = ha[3];
    uint4 b0 = hb[0], b1 = hb[1], b2q = hb[2], b3 = hb[3];
    h1_acc8(a0, S);
    h1_acc8(a1, S + 8);
    h1_acc8(a2, S + 16);
    h1_acc8(a3, S + 24);
    h1_acc8(b0, S);
    h1_acc8(b1, S + 8);
    h1_acc8(b2q, S + 16);
    h1_acc8(b3, S + 24);
  }
  if (e < r1) {
    int s = ntload_i(&srt[e]);
    const uint4* hp = (const uint4*)(H1u + (size_t)s * 16);
    uint4 q0 = hp[0], q1 = hp[1], q2 = hp[2], q3 = hp[3];
    h1_acc8(q0, S);
    h1_acc8(q1, S + 8);
    h1_acc8(q2, S + 16);
    h1_acc8(q3, S + 24);
  }
  float di = tp.w;
#pragma unroll
  for (int h = 0; h < HID; ++h) S[h] *= di;

  // z = S @ W2 + b2 in 4 chunks of 8; head folded per chunk.
  float d0 = bout[0], d1 = bout[1], dd2 = bout[2];
#pragma unroll
  for (int cz = 0; cz < HID / 8; ++cz) {
    float z[8];
#pragma unroll
    for (int j = 0; j < 8; ++j) z[j] = b2[cz * 8 + j];
#pragma unroll
    for (int h = 0; h < HID; ++h) {
      float a = S[h];
#pragma unroll
      for (int j = 0; j < 8; ++j) z[j] = fmaf(a, W2[h * HID + cz * 8 + j], z[j]);
    }
#pragma unroll
    for (int j = 0; j < 8; ++j) {
      float v = fmaxf(z[j], 0.0f);
      int hp = cz * 8 + j;
      d0 = fmaf(v, Wout[hp * 3 + 0], d0);
      d1 = fmaf(v, Wout[hp * 3 + 1], d1);
      dd2 = fmaf(v, Wout[hp * 3 + 2], dd2);
    }
  }

  ntstore_f(tp.x - d0, &o12[i]);
  ntstore_f(tp.y - d1, &o13[i]);
  ntstore_f(tp.z - dd2, &o23[i]);
  int a12 = ntload_i(&c12[i]);
  int a13 = ntload_i(&c13[i]);
  int a23 = ntload_i(&c23[i]);
  unsafeAtomicAdd(&oec[a12], d0);
  unsafeAtomicAdd(&oec[a13], d1);
  unsafeAtomicAdd(&oec[a23], dd2);
}

// ---------------- launch ----------------

extern "C" void kernel_launch(void* const* d_in, const int* in_sizes, int n_in,
                              void* d_out, int out_size, void* d_ws, size_t ws_size,
                              hipStream_t stream) {
  const float* ec  = (const float*)d_in[0];
  const float* t12 = (const float*)d_in[1];
  const float* t13 = (const float*)d_in[2];
  const float* t23 = (const float*)d_in[3];
  const int* c12   = (const int*)d_in[4];
  const int* c13   = (const int*)d_in[5];
  const int* c23   = (const int*)d_in[6];
  const float* cnt = (const float*)d_in[7];
  const int* ei    = (const int*)d_in[8];
  const float* W1  = (const float*)d_in[9];
  const float* b1  = (const float*)d_in[10];
  const float* W2  = (const float*)d_in[11];
  const float* b2  = (const float*)d_in[12];
  const float* Wout = (const float*)d_in[13];
  const float* bout = (const float*)d_in[14];

  const int E = in_sizes[0];
  const int T = in_sizes[1];
  const int M = in_sizes[8] / 2;
  const int NBK = (T + NPB - 1) / NPB;  // 512 for T=2M

  float* oec = (float*)d_out;
  float* o12 = oec + E;
  float* o13 = o12 + T;
  float* o23 = o13 + T;

  // workspace (~184 MB):
  // H1u (fp16 rows, T*64B = 128MB) | tri4[16B*T] | srt[M] | rptr[T+1] | gh | gboff | gcur
  // P (int2*M = 32MB) aliases H1u (dead after k_bfinal, H1 written in k_agg1h1).
  // msg (E floats = 4MB) also aliases H1u (written k_prep_e, dead after k_step1pack).
  uint*   H1u  = (uint*)d_ws;                    // T*16 uints = 128MB
  float4* tri4 = (float4*)(H1u + (size_t)T * 16);
  int*    srt  = (int*)(tri4 + T);
  int*    rptr = srt + M;
  int*    gh   = rptr + (T + 1);
  int*    gboff = gh + NBK;
  int*    gcur  = gboff + (NBK + 1);
  int2*   P    = (int2*)H1u;   // alias: dead before H1 written
  float*  msg  = (float*)H1u;  // alias: live only between k_prep_e and k_step1pack

  auto blocks = [](long n) { return (int)((n + BS - 1) / BS); };
  const int tiles = (M + EBT - 1) / EBT;

  // bucketed counting sort by dst -> row_ptr + srt
  k_zero_i<<<blocks(NBK), BS, 0, stream>>>(gh, NBK);
  k_bhist<<<tiles, BS, 0, stream>>>(ei, gh, M, NBK);
  k_bscan<<<1, BS, 0, stream>>>(gh, gboff, gcur, NBK);
  k_bscatter<<<tiles, BS, 0, stream>>>(ei, gcur, P, M, NBK);
  k_bfinal<<<NBK, BS, 0, stream>>>(P, gboff, rptr, srt, T, M, NBK);

  // per-edge prep (msg + output edge-cost init), then step-1 pack
  k_prep_e<<<blocks(E), BS, 0, stream>>>(ec, cnt, msg, oec, E);
  k_step1pack<<<blocks(T), BS, 0, stream>>>(msg, t12, t13, t23, c12, c13, c23,
                                            rptr, tri4, T);

  // layer 1 aggregate fused with h1 + dis scale -> fp16 H1 rows
  k_agg1h1<<<blocks(T), BS, 0, stream>>>(rptr, srt, tri4, H1u, W1, b1, T);

  // layer 2: direct CSR gather of H1 rows + W2 + head + scatter
  k_l2head<<<blocks(T), BS, 0, stream>>>(rptr, srt, H1u, tri4,
                                         W2, b2, Wout, bout,
                                         c12, c13, c23, o12, o13, o23, oec, T);
}

// Round 4
// 724.463 us; speedup vs baseline: 1.1732x; 1.0834x over previous
//
#include <hip/hip_runtime.h>
#include <hip/hip_fp16.h>
#include <math.h>

#define HID 32
#define BS 256

// ---- bucketed counting-sort parameters ----
#define NPB 4096          // nodes per bucket (dst range per bucket)
#define NBK_MAX 1024      // LDS sizing cap for bucket count
#define EBT 8192          // edges per scatter tile
#define CAP 11776         // per-bucket LDS srt capacity (mean 8192, +40 sigma)

// ---- packed half2 helpers (pure clang vector ops -> v_pk_* / v_dot2) ----
typedef _Float16 h2v __attribute__((ext_vector_type(2)));

__device__ __forceinline__ h2v u2h(uint u) { return __builtin_bit_cast(h2v, u); }
__device__ __forceinline__ uint h2u(h2v h) { return __builtin_bit_cast(uint, h); }
__device__ __forceinline__ h2v splat2(float x) {
  _Float16 h = (_Float16)x;
  h2v r; r.x = h; r.y = h; return r;
}
__device__ __forceinline__ uint pack2(float a, float b) {
  h2v r; r.x = (_Float16)a; r.y = (_Float16)b; return h2u(r);
}
// z += dot(half2 a, half2 b) with f32 accumulate (v_dot2_f32_f16)
__device__ __forceinline__ float dot2acc(uint a, uint b, float c) {
#if __has_builtin(__builtin_amdgcn_fdot2)
  return __builtin_amdgcn_fdot2(u2h(a), u2h(b), c, false);
#else
  h2v ah = u2h(a), bh = u2h(b);
  c = fmaf((float)ah.x, (float)bh.x, c);
  return fmaf((float)ah.y, (float)bh.y, c);
#endif
}

// ---------------- utility ----------------

__global__ void k_zero_i(int* __restrict__ p, int n) {
  int i = blockIdx.x * BS + threadIdx.x;
  if (i < n) p[i] = 0;
}

// ---------------- bucketed sort: pass A — global bucket histogram ----------------

__global__ __launch_bounds__(BS) void k_bhist(const int* __restrict__ ei,
                                              int* __restrict__ gh, int M, int NBK) {
  __shared__ int hist[NBK_MAX];
  for (int b = threadIdx.x; b < NBK; b += BS) hist[b] = 0;
  __syncthreads();
  int e0 = blockIdx.x * EBT;
  int n = min(EBT, M - e0);
  for (int k = threadIdx.x; k < n; k += BS) {
    int d = ei[M + e0 + k];
    atomicAdd(&hist[d / NPB], 1);
  }
  __syncthreads();
  for (int b = threadIdx.x; b < NBK; b += BS)
    if (hist[b]) atomicAdd(&gh[b], hist[b]);
}

// ---------------- pass B — single-block scan of bucket sizes ----------------

__global__ __launch_bounds__(BS) void k_bscan(const int* __restrict__ gh,
                                              int* __restrict__ gboff,
                                              int* __restrict__ gcur, int NBK) {
  __shared__ int part[BS];
  int C = (NBK + BS - 1) / BS;
  int s = 0;
  for (int k = 0; k < C; ++k) {
    int idx = threadIdx.x * C + k;
    if (idx < NBK) s += gh[idx];
  }
  part[threadIdx.x] = s;
  __syncthreads();
  for (int off = 1; off < BS; off <<= 1) {
    int v = part[threadIdx.x];
    int u = (threadIdx.x >= off) ? part[threadIdx.x - off] : 0;
    __syncthreads();
    part[threadIdx.x] = v + u;
    __syncthreads();
  }
  int run = (threadIdx.x > 0) ? part[threadIdx.x - 1] : 0;
  for (int k = 0; k < C; ++k) {
    int idx = threadIdx.x * C + k;
    if (idx < NBK) {
      gboff[idx] = run;
      gcur[idx] = run;
      run += gh[idx];
    }
  }
  if (threadIdx.x == BS - 1) gboff[NBK] = run;  // == M
}

// ---------------- pass C — tiled scatter of (src,dst) pairs into bucket runs ----------------

__global__ __launch_bounds__(BS) void k_bscatter(const int* __restrict__ ei,
                                                 int* __restrict__ gcur,
                                                 int2* __restrict__ P, int M, int NBK) {
  __shared__ int hist[NBK_MAX];
  __shared__ int excl[NBK_MAX];
  __shared__ int curs[NBK_MAX];
  __shared__ int base[NBK_MAX];
  __shared__ int part[BS];
  for (int b = threadIdx.x; b < NBK; b += BS) hist[b] = 0;
  __syncthreads();
  int e0 = blockIdx.x * EBT;
  int n = min(EBT, M - e0);
  for (int k = threadIdx.x; k < n; k += BS) {
    int d = ei[M + e0 + k];
    atomicAdd(&hist[d / NPB], 1);
  }
  __syncthreads();
  int C = (NBK + BS - 1) / BS;
  int s = 0;
  for (int k = 0; k < C; ++k) {
    int idx = threadIdx.x * C + k;
    if (idx < NBK) s += hist[idx];
  }
  part[threadIdx.x] = s;
  __syncthreads();
  for (int off = 1; off < BS; off <<= 1) {
    int v = part[threadIdx.x];
    int u = (threadIdx.x >= off) ? part[threadIdx.x - off] : 0;
    __syncthreads();
    part[threadIdx.x] = v + u;
    __syncthreads();
  }
  int run = (threadIdx.x > 0) ? part[threadIdx.x - 1] : 0;
  for (int k = 0; k < C; ++k) {
    int idx = threadIdx.x * C + k;
    if (idx < NBK) {
      excl[idx] = run;
      curs[idx] = run;
      run += hist[idx];
    }
  }
  __syncthreads();
  for (int b = threadIdx.x; b < NBK; b += BS)
    base[b] = hist[b] ? atomicAdd(&gcur[b], hist[b]) : 0;
  __syncthreads();
  for (int k = threadIdx.x; k < n; k += BS) {
    int sidx = ei[e0 + k];
    int d = ei[M + e0 + k];
    int b = d / NPB;
    int pos = atomicAdd(&curs[b], 1);
    int gpos = base[b] + (pos - excl[b]);
    P[gpos] = make_int2(sidx, d);
  }
}

// ---------------- pass D — per-bucket LDS counting sort -> row_ptr + srt ----------------

__global__ __launch_bounds__(BS) void k_bfinal(const int2* __restrict__ P,
                                               const int* __restrict__ gboff,
                                               int* __restrict__ row_ptr,
                                               int* __restrict__ srt, int T, int M,
                                               int NBK) {
  __shared__ int cnt[NPB];
  __shared__ int lsrt[CAP];
  __shared__ int part[BS];
  int b = blockIdx.x;
  int d0 = b * NPB;
  int nodesHere = min(NPB, T - d0);
  int p0 = gboff[b], p1 = gboff[b + 1];
  int nE = p1 - p0;
  for (int j = threadIdx.x; j < NPB; j += BS) cnt[j] = 0;
  __syncthreads();
  for (int j = threadIdx.x; j < nE; j += BS) {
    int2 p = P[p0 + j];
    atomicAdd(&cnt[p.y - d0], 1);
  }
  __syncthreads();
  const int CN = NPB / BS;  // 16
  int s = 0;
#pragma unroll
  for (int k = 0; k < CN; ++k) s += cnt[threadIdx.x * CN + k];
  part[threadIdx.x] = s;
  __syncthreads();
  for (int off = 1; off < BS; off <<= 1) {
    int v = part[threadIdx.x];
    int u = (threadIdx.x >= off) ? part[threadIdx.x - off] : 0;
    __syncthreads();
    part[threadIdx.x] = v + u;
    __syncthreads();
  }
  int run = (threadIdx.x > 0) ? part[threadIdx.x - 1] : 0;
#pragma unroll
  for (int k = 0; k < CN; ++k) {
    int idx = threadIdx.x * CN + k;
    int c = cnt[idx];
    cnt[idx] = run;
    if (idx < nodesHere) row_ptr[d0 + idx] = p0 + run;
    run += c;
  }
  if (b == NBK - 1 && threadIdx.x == 0) row_ptr[T] = M;
  __syncthreads();
  if (nE <= CAP) {
    for (int j = threadIdx.x; j < nE; j += BS) {
      int2 p = P[p0 + j];
      int pos = atomicAdd(&cnt[p.y - d0], 1);
      lsrt[pos] = p.x;
    }
    __syncthreads();
    for (int j = threadIdx.x; j < nE; j += BS) srt[p0 + j] = lsrt[j];
  } else {
    for (int j = threadIdx.x; j < nE; j += BS) {
      int2 p = P[p0 + j];
      int pos = atomicAdd(&cnt[p.y - d0], 1);
      srt[p0 + pos] = p.x;
    }
  }
}

// ---------------- math kernels ----------------

// msg[e] = ec[e]/cnt[e]; oec[e] = (cnt>0) ? 0 : ec  (one pass over E)
__global__ void k_prep_e(const float* __restrict__ ec, const float* __restrict__ cnt,
                         float* __restrict__ msg, float* __restrict__ oec, int E) {
  int i = blockIdx.x * BS + threadIdx.x;
  if (i >= E) return;
  float c = cnt[i], v = ec[i];
  msg[i] = v / c;
  oec[i] = (c > 0.0f) ? 0.0f : v;
}

// step 1: tri4[i] = (t12 + msg[c12], t13 + msg[c13], t23 + msg[c23], dis_i)
__global__ void k_step1pack(const float* __restrict__ msg,
                            const float* __restrict__ t12, const float* __restrict__ t13,
                            const float* __restrict__ t23,
                            const int* __restrict__ c12, const int* __restrict__ c13,
                            const int* __restrict__ c23,
                            const int* __restrict__ row_ptr,
                            float4* __restrict__ tri4, int T) {
  int i = blockIdx.x * BS + threadIdx.x;
  if (i >= T) return;
  int a = c12[i], b = c13[i], c = c23[i];
  float4 v;
  v.x = t12[i] + msg[a];
  v.y = t13[i] + msg[b];
  v.z = t23[i] + msg[c];
  v.w = rsqrtf((float)(row_ptr[i + 1] - row_ptr[i]) + 1.0f);
  tri4[i] = v;
}

// ---- pack weights to half2 (one-time, trivially cheap) ----
// layout in pkw (uint):
//  [0..47]    W1h[r*16+k]  = (W1[r][2k],   W1[r][2k+1])
//  [48..63]   b1h[k]       = (b1[2k],      b1[2k+1])
//  [64..575]  W2h[h2*32+j] = (W2[2h2][j],  W2[2h2+1][j])   (consecutive-h pairs for dot2)
__global__ void k_packw(const float* __restrict__ W1, const float* __restrict__ b1,
                        const float* __restrict__ W2, uint* __restrict__ pkw) {
  int i = blockIdx.x * BS + threadIdx.x;
  if (i < 48) {
    int r = i >> 4, k = i & 15;
    pkw[i] = pack2(W1[r * HID + 2 * k], W1[r * HID + 2 * k + 1]);
  } else if (i < 64) {
    int k = i - 48;
    pkw[i] = pack2(b1[2 * k], b1[2 * k + 1]);
  } else if (i < 576) {
    int idx = i - 64;
    int h2 = idx >> 5, j = idx & 31;
    pkw[i] = pack2(W2[(2 * h2) * HID + j], W2[(2 * h2 + 1) * HID + j]);
  }
}

// ---- layer-1 aggregate (pre-W1, linearity) -> G4 = (ax,ay,az,di), 16B rows ----
// 32MB table: L2/L3-resident for the layer-2 random gather (R0 measured FETCH 79MB).
__global__ __launch_bounds__(BS) void k_agg1c(const int* __restrict__ row_ptr,
                                              const int* __restrict__ srt,
                                              const float4* __restrict__ tri4,
                                              float4* __restrict__ G4, int T) {
  int i = blockIdx.x * BS + threadIdx.x;
  if (i >= T) return;
  int r0 = row_ptr[i], r1 = row_ptr[i + 1];
  float4 ts = tri4[i];
  float di = ts.w;
  float d2 = di * di;
  float ax = ts.x * d2, ay = ts.y * d2, az = ts.z * d2;
  int e = r0;
  for (; e + 4 <= r1; e += 4) {
    int s0 = srt[e + 0];
    int s1 = srt[e + 1];
    int s2 = srt[e + 2];
    int s3 = srt[e + 3];
    float4 v0 = tri4[s0];
    float4 v1 = tri4[s1];
    float4 v2 = tri4[s2];
    float4 v3 = tri4[s3];
    float w0 = v0.w * di, w1 = v1.w * di, w2 = v2.w * di, w3 = v3.w * di;
    ax = fmaf(v0.x, w0, ax); ay = fmaf(v0.y, w0, ay); az = fmaf(v0.z, w0, az);
    ax = fmaf(v1.x, w1, ax); ay = fmaf(v1.y, w1, ay); az = fmaf(v1.z, w1, az);
    ax = fmaf(v2.x, w2, ax); ay = fmaf(v2.y, w2, ay); az = fmaf(v2.z, w2, az);
    ax = fmaf(v3.x, w3, ax); ay = fmaf(v3.y, w3, ay); az = fmaf(v3.z, w3, az);
  }
  for (; e < r1; ++e) {
    float4 v = tri4[srt[e]];
    float w = v.w * di;
    ax = fmaf(v.x, w, ax);
    ay = fmaf(v.y, w, ay);
    az = fmaf(v.z, w, az);
  }
  float4 o;
  o.x = ax; o.y = ay; o.z = az; o.w = di;
  G4[i] = o;
}

// per-edge packed h1 expand + f32 mix-accumulate:
// S[2k.. ] += relu((gx,gy,gz)@W1 + b1)[2k..] * w     (~103 VALU vs 160 scalar f32)
__device__ __forceinline__ void edge_h1_acc(float gx, float gy, float gz, float w,
                                            const uint* __restrict__ W1s,
                                            const uint* __restrict__ b1s,
                                            float* S) {
  h2v hx = splat2(gx), hy = splat2(gy), hz = splat2(gz);
  h2v zero; zero.x = (_Float16)0.f; zero.y = (_Float16)0.f;
#pragma unroll
  for (int k = 0; k < 16; ++k) {
    h2v t = hx * u2h(W1s[k]) + (hy * u2h(W1s[16 + k]) + (hz * u2h(W1s[32 + k]) + u2h(b1s[k])));
    t = __builtin_elementwise_max(t, zero);
    // f16 -> f32 extend folds into v_fma_mix (f32 accumulate, no precision loss)
    S[2 * k]     = fmaf((float)t.x, w, S[2 * k]);
    S[2 * k + 1] = fmaf((float)t.y, w, S[2 * k + 1]);
  }
}

// fused layer-2 (recompute-h1 from 16B G4 gathers) + packed W2 + head + scatter.
// R3 post-mortem: the 64B H1-row gather was a traffic wall (362us flat across
// 16/24/32-wave configs). Recompute path (R0) was VALU-bound at 340us with
// scalar f32; packed f16 (pk_fma + v_dot2_f32_f16, f32 accumulators) cuts the
// op count ~1.8x. Weights pre-packed to half2 (k_packw) -> wave-uniform s_loads.
__global__ __launch_bounds__(BS, 6) void k_l2head(
    const int* __restrict__ row_ptr, const int* __restrict__ srt,
    const float4* __restrict__ G4, const float4* __restrict__ tri4,
    const uint* __restrict__ pkw,
    const float* __restrict__ b2,
    const float* __restrict__ Wout, const float* __restrict__ bout,
    const int* __restrict__ c12, const int* __restrict__ c13,
    const int* __restrict__ c23,
    float* __restrict__ o12, float* __restrict__ o13, float* __restrict__ o23,
    float* __restrict__ oec, int T) {
  int i = blockIdx.x * BS + threadIdx.x;
  if (i >= T) return;
  int r0 = row_ptr[i], r1 = row_ptr[i + 1];
  float4 gi = G4[i];
  float di = gi.w;
  float4 tp = tri4[i];
  const uint* W1s = pkw;        // 48 u32
  const uint* b1s = pkw + 48;   // 16 u32
  const uint* W2s = pkw + 64;   // 512 u32

  float S[HID];
#pragma unroll
  for (int h = 0; h < HID; ++h) S[h] = 0.0f;

  // self-loop term: h1(G_i) * di^2
  edge_h1_acc(gi.x, gi.y, gi.z, di * di, W1s, b1s, S);

  // edge terms: h1(G_src) * (d_src * d_i); 2-wide so both 16B gathers are in flight
  int e = r0;
  for (; e + 2 <= r1; e += 2) {
    int s0 = srt[e + 0];
    int s1 = srt[e + 1];
    float4 v0 = G4[s0];
    float4 v1 = G4[s1];
    edge_h1_acc(v0.x, v0.y, v0.z, v0.w * di, W1s, b1s, S);
    edge_h1_acc(v1.x, v1.y, v1.z, v1.w * di, W1s, b1s, S);
  }
  if (e < r1) {
    float4 v = G4[srt[e]];
    edge_h1_acc(v.x, v.y, v.z, v.w * di, W1s, b1s, S);
  }

  // pack S once into consecutive-h half2 pairs for dot2
  uint sh[16];
#pragma unroll
  for (int k = 0; k < 16; ++k) sh[k] = pack2(S[2 * k], S[2 * k + 1]);

  // z = S @ W2 + b2 via v_dot2_f32_f16 (f32 accumulate); head folded per chunk of 8
  float d0 = bout[0], d1 = bout[1], dd2 = bout[2];
#pragma unroll
  for (int cz = 0; cz < 4; ++cz) {
    float z[8];
#pragma unroll
    for (int j = 0; j < 8; ++j) z[j] = b2[cz * 8 + j];
#pragma unroll
    for (int h2 = 0; h2 < 16; ++h2) {
#pragma unroll
      for (int j = 0; j < 8; ++j)
        z[j] = dot2acc(sh[h2], W2s[h2 * HID + cz * 8 + j], z[j]);
    }
#pragma unroll
    for (int j = 0; j < 8; ++j) {
      float v = fmaxf(z[j], 0.0f);
      int jp = cz * 8 + j;
      d0  = fmaf(v, Wout[jp * 3 + 0], d0);
      d1  = fmaf(v, Wout[jp * 3 + 1], d1);
      dd2 = fmaf(v, Wout[jp * 3 + 2], dd2);
    }
  }

  o12[i] = tp.x - d0;
  o13[i] = tp.y - d1;
  o23[i] = tp.z - dd2;
  unsafeAtomicAdd(&oec[c12[i]], d0);
  unsafeAtomicAdd(&oec[c13[i]], d1);
  unsafeAtomicAdd(&oec[c23[i]], dd2);
}

// ---------------- launch ----------------

extern "C" void kernel_launch(void* const* d_in, const int* in_sizes, int n_in,
                              void* d_out, int out_size, void* d_ws, size_t ws_size,
                              hipStream_t stream) {
  const float* ec  = (const float*)d_in[0];
  const float* t12 = (const float*)d_in[1];
  const float* t13 = (const float*)d_in[2];
  const float* t23 = (const float*)d_in[3];
  const int* c12   = (const int*)d_in[4];
  const int* c13   = (const int*)d_in[5];
  const int* c23   = (const int*)d_in[6];
  const float* cnt = (const float*)d_in[7];
  const int* ei    = (const int*)d_in[8];
  const float* W1  = (const float*)d_in[9];
  const float* b1  = (const float*)d_in[10];
  const float* W2  = (const float*)d_in[11];
  const float* b2  = (const float*)d_in[12];
  const float* Wout = (const float*)d_in[13];
  const float* bout = (const float*)d_in[14];

  const int E = in_sizes[0];
  const int T = in_sizes[1];
  const int M = in_sizes[8] / 2;
  const int NBK = (T + NPB - 1) / NPB;  // 512 for T=2M

  float* oec = (float*)d_out;
  float* o12 = oec + E;
  float* o13 = o12 + T;
  float* o23 = o13 + T;

  // workspace (~92 MB):
  // tri4[16B*T]=32MB | G4[16B*T]=32MB | srt[M]=16MB | rptr[T+1] | msg[E] | gh | gboff | gcur | pkw[576]
  // P (int2*M = 32MB) aliases G4 (P dead after k_bfinal; G4 written in k_agg1c).
  float4* tri4 = (float4*)d_ws;
  float4* G4   = tri4 + T;
  int*    srt  = (int*)(G4 + T);
  int*    rptr = srt + M;
  float*  msg  = (float*)(rptr + (T + 1));
  int*    gh   = (int*)(msg + E);
  int*    gboff = gh + NBK;
  int*    gcur  = gboff + (NBK + 1);
  uint*   pkw   = (uint*)(gcur + NBK);
  int2*   P    = (int2*)G4;  // alias: dead before G4 written

  auto blocks = [](long n) { return (int)((n + BS - 1) / BS); };
  const int tiles = (M + EBT - 1) / EBT;

  // bucketed counting sort by dst -> row_ptr + srt
  k_zero_i<<<blocks(NBK), BS, 0, stream>>>(gh, NBK);
  k_bhist<<<tiles, BS, 0, stream>>>(ei, gh, M, NBK);
  k_bscan<<<1, BS, 0, stream>>>(gh, gboff, gcur, NBK);
  k_bscatter<<<tiles, BS, 0, stream>>>(ei, gcur, P, M, NBK);
  k_bfinal<<<NBK, BS, 0, stream>>>(P, gboff, rptr, srt, T, M, NBK);

  // pack weights (tiny), per-edge prep, step-1 pack
  k_packw<<<3, BS, 0, stream>>>(W1, b1, W2, pkw);
  k_prep_e<<<blocks(E), BS, 0, stream>>>(ec, cnt, msg, oec, E);
  k_step1pack<<<blocks(T), BS, 0, stream>>>(msg, t12, t13, t23, c12, c13, c23,
                                            rptr, tri4, T);

  // layer 1 aggregate (pre-W1) -> G4
  k_agg1c<<<blocks(T), BS, 0, stream>>>(rptr, srt, tri4, G4, T);

  // layer 2: gather 16B G4 rows, packed-f16 h1 recompute + dot2 W2 + head + scatter
  k_l2head<<<blocks(T), BS, 0, stream>>>(rptr, srt, G4, tri4, pkw,
                                         b2, Wout, bout,
                                         c12, c13, c23, o12, o13, o23, oec, T);
}

// Round 5
// 709.128 us; speedup vs baseline: 1.1986x; 1.0216x over previous
//
#include <hip/hip_runtime.h>
#include <hip/hip_fp16.h>
#include <math.h>

#define HID 32
#define BS 256

// ---- bucketed counting-sort parameters ----
#define NPB 4096          // nodes per bucket (dst range per bucket)
#define NBK_MAX 1024      // LDS sizing cap for bucket count
#define EBT 8192          // edges per scatter tile
#define CAP 11776         // per-bucket LDS srt capacity (mean 8192, +40 sigma)

// ---- packed half2 helpers (pure clang vector ops -> v_pk_* / v_dot2) ----
typedef _Float16 h2v __attribute__((ext_vector_type(2)));

__device__ __forceinline__ h2v u2h(uint u) { return __builtin_bit_cast(h2v, u); }
__device__ __forceinline__ uint h2u(h2v h) { return __builtin_bit_cast(uint, h); }
__device__ __forceinline__ uint pack2(float a, float b) {
  h2v r; r.x = (_Float16)a; r.y = (_Float16)b; return h2u(r);
}
// z += dot(half2 a, half2 b) with f32 accumulate (v_dot2_f32_f16)
__device__ __forceinline__ float dot2acc(uint a, uint b, float c) {
#if __has_builtin(__builtin_amdgcn_fdot2)
  return __builtin_amdgcn_fdot2(u2h(a), u2h(b), c, false);
#else
  h2v ah = u2h(a), bh = u2h(b);
  c = fmaf((float)ah.x, (float)bh.x, c);
  return fmaf((float)ah.y, (float)bh.y, c);
#endif
}
// extract the .w half (dis) of an 8B half4 row
__device__ __forceinline__ float h4w(uint2 g) {
  h2v hi = u2h(g.y); return (float)hi.y;
}

// ---------------- utility ----------------

__global__ void k_zero_i(int* __restrict__ p, int n) {
  int i = blockIdx.x * BS + threadIdx.x;
  if (i < n) p[i] = 0;
}

// ---------------- bucketed sort: pass A — global bucket histogram ----------------

__global__ __launch_bounds__(BS) void k_bhist(const int* __restrict__ ei,
                                              int* __restrict__ gh, int M, int NBK) {
  __shared__ int hist[NBK_MAX];
  for (int b = threadIdx.x; b < NBK; b += BS) hist[b] = 0;
  __syncthreads();
  int e0 = blockIdx.x * EBT;
  int n = min(EBT, M - e0);
  for (int k = threadIdx.x; k < n; k += BS) {
    int d = ei[M + e0 + k];
    atomicAdd(&hist[d / NPB], 1);
  }
  __syncthreads();
  for (int b = threadIdx.x; b < NBK; b += BS)
    if (hist[b]) atomicAdd(&gh[b], hist[b]);
}

// ---------------- pass B — single-block scan of bucket sizes ----------------

__global__ __launch_bounds__(BS) void k_bscan(const int* __restrict__ gh,
                                              int* __restrict__ gboff,
                                              int* __restrict__ gcur, int NBK) {
  __shared__ int part[BS];
  int C = (NBK + BS - 1) / BS;
  int s = 0;
  for (int k = 0; k < C; ++k) {
    int idx = threadIdx.x * C + k;
    if (idx < NBK) s += gh[idx];
  }
  part[threadIdx.x] = s;
  __syncthreads();
  for (int off = 1; off < BS; off <<= 1) {
    int v = part[threadIdx.x];
    int u = (threadIdx.x >= off) ? part[threadIdx.x - off] : 0;
    __syncthreads();
    part[threadIdx.x] = v + u;
    __syncthreads();
  }
  int run = (threadIdx.x > 0) ? part[threadIdx.x - 1] : 0;
  for (int k = 0; k < C; ++k) {
    int idx = threadIdx.x * C + k;
    if (idx < NBK) {
      gboff[idx] = run;
      gcur[idx] = run;
      run += gh[idx];
    }
  }
  if (threadIdx.x == BS - 1) gboff[NBK] = run;  // == M
}

// ---------------- pass C — tiled scatter of (src,dst) pairs into bucket runs ----------------

__global__ __launch_bounds__(BS) void k_bscatter(const int* __restrict__ ei,
                                                 int* __restrict__ gcur,
                                                 int2* __restrict__ P, int M, int NBK) {
  __shared__ int hist[NBK_MAX];
  __shared__ int excl[NBK_MAX];
  __shared__ int curs[NBK_MAX];
  __shared__ int base[NBK_MAX];
  __shared__ int part[BS];
  for (int b = threadIdx.x; b < NBK; b += BS) hist[b] = 0;
  __syncthreads();
  int e0 = blockIdx.x * EBT;
  int n = min(EBT, M - e0);
  for (int k = threadIdx.x; k < n; k += BS) {
    int d = ei[M + e0 + k];
    atomicAdd(&hist[d / NPB], 1);
  }
  __syncthreads();
  int C = (NBK + BS - 1) / BS;
  int s = 0;
  for (int k = 0; k < C; ++k) {
    int idx = threadIdx.x * C + k;
    if (idx < NBK) s += hist[idx];
  }
  part[threadIdx.x] = s;
  __syncthreads();
  for (int off = 1; off < BS; off <<= 1) {
    int v = part[threadIdx.x];
    int u = (threadIdx.x >= off) ? part[threadIdx.x - off] : 0;
    __syncthreads();
    part[threadIdx.x] = v + u;
    __syncthreads();
  }
  int run = (threadIdx.x > 0) ? part[threadIdx.x - 1] : 0;
  for (int k = 0; k < C; ++k) {
    int idx = threadIdx.x * C + k;
    if (idx < NBK) {
      excl[idx] = run;
      curs[idx] = run;
      run += hist[idx];
    }
  }
  __syncthreads();
  for (int b = threadIdx.x; b < NBK; b += BS)
    base[b] = hist[b] ? atomicAdd(&gcur[b], hist[b]) : 0;
  __syncthreads();
  for (int k = threadIdx.x; k < n; k += BS) {
    int sidx = ei[e0 + k];
    int d = ei[M + e0 + k];
    int b = d / NPB;
    int pos = atomicAdd(&curs[b], 1);
    int gpos = base[b] + (pos - excl[b]);
    P[gpos] = make_int2(sidx, d);
  }
}

// ---------------- pass D — per-bucket LDS counting sort -> row_ptr + srt ----------------

__global__ __launch_bounds__(BS) void k_bfinal(const int2* __restrict__ P,
                                               const int* __restrict__ gboff,
                                               int* __restrict__ row_ptr,
                                               int* __restrict__ srt, int T, int M,
                                               int NBK) {
  __shared__ int cnt[NPB];
  __shared__ int lsrt[CAP];
  __shared__ int part[BS];
  int b = blockIdx.x;
  int d0 = b * NPB;
  int nodesHere = min(NPB, T - d0);
  int p0 = gboff[b], p1 = gboff[b + 1];
  int nE = p1 - p0;
  for (int j = threadIdx.x; j < NPB; j += BS) cnt[j] = 0;
  __syncthreads();
  for (int j = threadIdx.x; j < nE; j += BS) {
    int2 p = P[p0 + j];
    atomicAdd(&cnt[p.y - d0], 1);
  }
  __syncthreads();
  const int CN = NPB / BS;  // 16
  int s = 0;
#pragma unroll
  for (int k = 0; k < CN; ++k) s += cnt[threadIdx.x * CN + k];
  part[threadIdx.x] = s;
  __syncthreads();
  for (int off = 1; off < BS; off <<= 1) {
    int v = part[threadIdx.x];
    int u = (threadIdx.x >= off) ? part[threadIdx.x - off] : 0;
    __syncthreads();
    part[threadIdx.x] = v + u;
    __syncthreads();
  }
  int run = (threadIdx.x > 0) ? part[threadIdx.x - 1] : 0;
#pragma unroll
  for (int k = 0; k < CN; ++k) {
    int idx = threadIdx.x * CN + k;
    int c = cnt[idx];
    cnt[idx] = run;
    if (idx < nodesHere) row_ptr[d0 + idx] = p0 + run;
    run += c;
  }
  if (b == NBK - 1 && threadIdx.x == 0) row_ptr[T] = M;
  __syncthreads();
  if (nE <= CAP) {
    for (int j = threadIdx.x; j < nE; j += BS) {
      int2 p = P[p0 + j];
      int pos = atomicAdd(&cnt[p.y - d0], 1);
      lsrt[pos] = p.x;
    }
    __syncthreads();
    for (int j = threadIdx.x; j < nE; j += BS) srt[p0 + j] = lsrt[j];
  } else {
    for (int j = threadIdx.x; j < nE; j += BS) {
      int2 p = P[p0 + j];
      int pos = atomicAdd(&cnt[p.y - d0], 1);
      srt[p0 + pos] = p.x;
    }
  }
}

// ---------------- math kernels ----------------

// msg[e] = ec[e]/cnt[e]; oec[e] = (cnt>0) ? 0 : ec  (one pass over E)
__global__ void k_prep_e(const float* __restrict__ ec, const float* __restrict__ cnt,
                         float* __restrict__ msg, float* __restrict__ oec, int E) {
  int i = blockIdx.x * BS + threadIdx.x;
  if (i >= E) return;
  float c = cnt[i], v = ec[i];
  msg[i] = v / c;
  oec[i] = (c > 0.0f) ? 0.0f : v;
}

// step 1: tri4[i] = (t12+msg, t13+msg, t23+msg, dis_i)  (f32, for self/outputs)
//         trih[i] = same row packed half4 (8B, gather table for layer 1)
__global__ void k_step1pack(const float* __restrict__ msg,
                            const float* __restrict__ t12, const float* __restrict__ t13,
                            const float* __restrict__ t23,
                            const int* __restrict__ c12, const int* __restrict__ c13,
                            const int* __restrict__ c23,
                            const int* __restrict__ row_ptr,
                            float4* __restrict__ tri4, uint2* __restrict__ trih, int T) {
  int i = blockIdx.x * BS + threadIdx.x;
  if (i >= T) return;
  int a = c12[i], b = c13[i], c = c23[i];
  float4 v;
  v.x = t12[i] + msg[a];
  v.y = t13[i] + msg[b];
  v.z = t23[i] + msg[c];
  v.w = rsqrtf((float)(row_ptr[i + 1] - row_ptr[i]) + 1.0f);
  tri4[i] = v;
  uint2 h;
  h.x = pack2(v.x, v.y);
  h.y = pack2(v.z, v.w);
  trih[i] = h;
}

// ---- pack weights to half2 (one-time, trivially cheap) ----
// layout in pkw (uint):
//  [0..47]    W1h[r*16+k]  = (W1[r][2k],   W1[r][2k+1])
//  [48..63]   b1h[k]       = (b1[2k],      b1[2k+1])
//  [64..575]  W2h[h2*32+j] = (W2[2h2][j],  W2[2h2+1][j])   (consecutive-h pairs for dot2)
__global__ void k_packw(const float* __restrict__ W1, const float* __restrict__ b1,
                        const float* __restrict__ W2, uint* __restrict__ pkw) {
  int i = blockIdx.x * BS + threadIdx.x;
  if (i < 48) {
    int r = i >> 4, k = i & 15;
    pkw[i] = pack2(W1[r * HID + 2 * k], W1[r * HID + 2 * k + 1]);
  } else if (i < 64) {
    int k = i - 48;
    pkw[i] = pack2(b1[2 * k], b1[2 * k + 1]);
  } else if (i < 576) {
    int idx = i - 64;
    int h2 = idx >> 5, j = idx & 31;
    pkw[i] = pack2(W2[(2 * h2) * HID + j], W2[(2 * h2 + 1) * HID + j]);
  }
}

// accumulate one gathered half4 tri row: (ax,ay,az) += tri.xyz * (tri.w * di)
__device__ __forceinline__ void acc3(uint2 g, float di, float& ax, float& ay, float& az) {
  h2v lo = u2h(g.x), hi = u2h(g.y);
  float w = (float)hi.y * di;
  ax = fmaf((float)lo.x, w, ax);
  ay = fmaf((float)lo.y, w, ay);
  az = fmaf((float)hi.x, w, az);
}

// ---- layer-1 aggregate (pre-W1, linearity) -> G4h = half4(ax,ay,az,di), 8B rows ----
// 8B gather rows halve the random-line footprint (16MB table) vs f32 rows.
__global__ __launch_bounds__(BS) void k_agg1c(const int* __restrict__ row_ptr,
                                              const int* __restrict__ srt,
                                              const float4* __restrict__ tri4,
                                              const uint2* __restrict__ trih,
                                              uint2* __restrict__ G4h, int T) {
  int i = blockIdx.x * BS + threadIdx.x;
  if (i >= T) return;
  int r0 = row_ptr[i], r1 = row_ptr[i + 1];
  float4 ts = tri4[i];
  float di = ts.w;
  float d2 = di * di;
  float ax = ts.x * d2, ay = ts.y * d2, az = ts.z * d2;
  int e = r0;
  for (; e + 4 <= r1; e += 4) {
    int s0 = srt[e + 0];
    int s1 = srt[e + 1];
    int s2 = srt[e + 2];
    int s3 = srt[e + 3];
    uint2 g0 = trih[s0];
    uint2 g1 = trih[s1];
    uint2 g2 = trih[s2];
    uint2 g3 = trih[s3];
    acc3(g0, di, ax, ay, az);
    acc3(g1, di, ax, ay, az);
    acc3(g2, di, ax, ay, az);
    acc3(g3, di, ax, ay, az);
  }
  for (; e < r1; ++e) {
    uint2 g = trih[srt[e]];
    acc3(g, di, ax, ay, az);
  }
  uint2 o;
  o.x = pack2(ax, ay);
  o.y = pack2(az, di);
  G4h[i] = o;
}

// per-edge packed h1 expand + f32 mix-accumulate from an 8B half4 G row:
// S[2k..] += relu((gx,gy,gz)@W1 + b1)[2k..] * w
__device__ __forceinline__ void edge_h1_accu(uint2 g, float w,
                                             const uint* __restrict__ W1s,
                                             const uint* __restrict__ b1s,
                                             float* S) {
  h2v lo = u2h(g.x), hi = u2h(g.y);
  h2v hx; hx.x = lo.x; hx.y = lo.x;
  h2v hy; hy.x = lo.y; hy.y = lo.y;
  h2v hz; hz.x = hi.x; hz.y = hi.x;
  h2v zero; zero.x = (_Float16)0.f; zero.y = (_Float16)0.f;
#pragma unroll
  for (int k = 0; k < 16; ++k) {
    h2v t = hx * u2h(W1s[k]) + (hy * u2h(W1s[16 + k]) + (hz * u2h(W1s[32 + k]) + u2h(b1s[k])));
    t = __builtin_elementwise_max(t, zero);
    // f16 -> f32 extend folds into v_fma_mix (f32 accumulate)
    S[2 * k]     = fmaf((float)t.x, w, S[2 * k]);
    S[2 * k + 1] = fmaf((float)t.y, w, S[2 * k + 1]);
  }
}

// fused layer-2 (recompute-h1 from 8B G4h gathers) + packed W2 + head + scatter.
// R4 post-mortem: VALU fixed (74->28%) but FETCH 307MB revealed the 64B-line
// amplification of the 16B random gather (32MB table >> 4MB/XCD L2). This round:
// 8B rows (16MB table -> better hit rate) + 4-wide gather ladder (4 lines in
// flight per lane; Poisson(2) degrees mean 95% of rows need one load round) +
// (BS,4) so the allocator has headroom (no R2-style spills).
__global__ __launch_bounds__(BS, 4) void k_l2head(
    const int* __restrict__ row_ptr, const int* __restrict__ srt,
    const uint2* __restrict__ G4h, const float4* __restrict__ tri4,
    const uint* __restrict__ pkw,
    const float* __restrict__ b2,
    const float* __restrict__ Wout, const float* __restrict__ bout,
    const int* __restrict__ c12, const int* __restrict__ c13,
    const int* __restrict__ c23,
    float* __restrict__ o12, float* __restrict__ o13, float* __restrict__ o23,
    float* __restrict__ oec, int T) {
  int i = blockIdx.x * BS + threadIdx.x;
  if (i >= T) return;
  int r0 = row_ptr[i], r1 = row_ptr[i + 1];
  uint2 gs = G4h[i];
  float4 tp = tri4[i];
  float di = tp.w;
  const uint* W1s = pkw;        // 48 u32
  const uint* b1s = pkw + 48;   // 16 u32
  const uint* W2s = pkw + 64;   // 512 u32

  float S[HID];
#pragma unroll
  for (int h = 0; h < HID; ++h) S[h] = 0.0f;

  // self-loop term: h1(G_i) * di^2
  edge_h1_accu(gs, di * di, W1s, b1s, S);

  // edge terms: h1(G_src) * (d_src * d_i); 4/2/1 ladder keeps up to 4 random
  // 8B loads in flight before any h1 math.
  int e = r0;
  for (; e + 4 <= r1; e += 4) {
    int s0 = srt[e + 0];
    int s1 = srt[e + 1];
    int s2 = srt[e + 2];
    int s3 = srt[e + 3];
    uint2 g0 = G4h[s0];
    uint2 g1 = G4h[s1];
    uint2 g2 = G4h[s2];
    uint2 g3 = G4h[s3];
    float w0 = h4w(g0) * di;
    float w1 = h4w(g1) * di;
    float w2 = h4w(g2) * di;
    float w3 = h4w(g3) * di;
    edge_h1_accu(g0, w0, W1s, b1s, S);
    edge_h1_accu(g1, w1, W1s, b1s, S);
    edge_h1_accu(g2, w2, W1s, b1s, S);
    edge_h1_accu(g3, w3, W1s, b1s, S);
  }
  if (e + 2 <= r1) {
    int s0 = srt[e + 0];
    int s1 = srt[e + 1];
    uint2 g0 = G4h[s0];
    uint2 g1 = G4h[s1];
    float w0 = h4w(g0) * di;
    float w1 = h4w(g1) * di;
    edge_h1_accu(g0, w0, W1s, b1s, S);
    edge_h1_accu(g1, w1, W1s, b1s, S);
    e += 2;
  }
  if (e < r1) {
    uint2 g = G4h[srt[e]];
    edge_h1_accu(g, h4w(g) * di, W1s, b1s, S);
  }

  // pack S once into consecutive-h half2 pairs for dot2
  uint sh[16];
#pragma unroll
  for (int k = 0; k < 16; ++k) sh[k] = pack2(S[2 * k], S[2 * k + 1]);

  // z = S @ W2 + b2 via v_dot2_f32_f16 (f32 accumulate); head folded per chunk of 8
  float d0 = bout[0], d1 = bout[1], dd2 = bout[2];
#pragma unroll
  for (int cz = 0; cz < 4; ++cz) {
    float z[8];
#pragma unroll
    for (int j = 0; j < 8; ++j) z[j] = b2[cz * 8 + j];
#pragma unroll
    for (int h2 = 0; h2 < 16; ++h2) {
#pragma unroll
      for (int j = 0; j < 8; ++j)
        z[j] = dot2acc(sh[h2], W2s[h2 * HID + cz * 8 + j], z[j]);
    }
#pragma unroll
    for (int j = 0; j < 8; ++j) {
      float v = fmaxf(z[j], 0.0f);
      int jp = cz * 8 + j;
      d0  = fmaf(v, Wout[jp * 3 + 0], d0);
      d1  = fmaf(v, Wout[jp * 3 + 1], d1);
      dd2 = fmaf(v, Wout[jp * 3 + 2], dd2);
    }
  }

  o12[i] = tp.x - d0;
  o13[i] = tp.y - d1;
  o23[i] = tp.z - dd2;
  unsafeAtomicAdd(&oec[c12[i]], d0);
  unsafeAtomicAdd(&oec[c13[i]], d1);
  unsafeAtomicAdd(&oec[c23[i]], dd2);
}

// ---------------- launch ----------------

extern "C" void kernel_launch(void* const* d_in, const int* in_sizes, int n_in,
                              void* d_out, int out_size, void* d_ws, size_t ws_size,
                              hipStream_t stream) {
  const float* ec  = (const float*)d_in[0];
  const float* t12 = (const float*)d_in[1];
  const float* t13 = (const float*)d_in[2];
  const float* t23 = (const float*)d_in[3];
  const int* c12   = (const int*)d_in[4];
  const int* c13   = (const int*)d_in[5];
  const int* c23   = (const int*)d_in[6];
  const float* cnt = (const float*)d_in[7];
  const int* ei    = (const int*)d_in[8];
  const float* W1  = (const float*)d_in[9];
  const float* b1  = (const float*)d_in[10];
  const float* W2  = (const float*)d_in[11];
  const float* b2  = (const float*)d_in[12];
  const float* Wout = (const float*)d_in[13];
  const float* bout = (const float*)d_in[14];

  const int E = in_sizes[0];
  const int T = in_sizes[1];
  const int M = in_sizes[8] / 2;
  const int NBK = (T + NPB - 1) / NPB;  // 512 for T=2M

  float* oec = (float*)d_out;
  float* o12 = oec + E;
  float* o13 = o12 + T;
  float* o23 = o13 + T;

  // workspace (~92 MB):
  // tri4 (32MB, f32) | trih (16MB, half4) | G4h (16MB, half4) | srt (16MB) |
  // rptr (8MB) | msg (4MB) | gh | gboff | gcur | pkw[576]
  // P (int2*M = 32MB) aliases tri4 (P dead after k_bfinal; tri4 written in k_step1pack).
  float4* tri4 = (float4*)d_ws;
  uint2*  trih = (uint2*)(tri4 + T);
  uint2*  G4h  = trih + T;
  int*    srt  = (int*)(G4h + T);
  int*    rptr = srt + M;
  float*  msg  = (float*)(rptr + (T + 1));
  int*    gh   = (int*)(msg + E);
  int*    gboff = gh + NBK;
  int*    gcur  = gboff + (NBK + 1);
  uint*   pkw   = (uint*)(gcur + NBK);
  int2*   P    = (int2*)tri4;  // alias: dead before tri4 written

  auto blocks = [](long n) { return (int)((n + BS - 1) / BS); };
  const int tiles = (M + EBT - 1) / EBT;

  // bucketed counting sort by dst -> row_ptr + srt
  k_zero_i<<<blocks(NBK), BS, 0, stream>>>(gh, NBK);
  k_bhist<<<tiles, BS, 0, stream>>>(ei, gh, M, NBK);
  k_bscan<<<1, BS, 0, stream>>>(gh, gboff, gcur, NBK);
  k_bscatter<<<tiles, BS, 0, stream>>>(ei, gcur, P, M, NBK);
  k_bfinal<<<NBK, BS, 0, stream>>>(P, gboff, rptr, srt, T, M, NBK);

  // pack weights (tiny), per-edge prep, step-1 pack (f32 + half4 copies)
  k_packw<<<3, BS, 0, stream>>>(W1, b1, W2, pkw);
  k_prep_e<<<blocks(E), BS, 0, stream>>>(ec, cnt, msg, oec, E);
  k_step1pack<<<blocks(T), BS, 0, stream>>>(msg, t12, t13, t23, c12, c13, c23,
                                            rptr, tri4, trih, T);

  // layer 1 aggregate (pre-W1) -> half4 G rows
  k_agg1c<<<blocks(T), BS, 0, stream>>>(rptr, srt, tri4, trih, G4h, T);

  // layer 2: gather 8B G rows, packed-f16 h1 recompute + dot2 W2 + head + scatter
  k_l2head<<<blocks(T), BS, 0, stream>>>(rptr, srt, G4h, tri4, pkw,
                                         b2, Wout, bout,
                                         c12, c13, c23, o12, o13, o23, oec, T);
}